// Round 1
// baseline (1614.304 us; speedup 1.0000x reference)
//
#include <hip/hip_runtime.h>
#include <cstddef>

#define DM 192
#define DI 384
#define DS 16
#define DR 12
#define L 1024
#define ROWS 4096   // B*N = 4*1024

// ---------------- helpers ----------------
__device__ __forceinline__ float wave_sum(float v) {
  #pragma unroll
  for (int off = 32; off > 0; off >>= 1) v += __shfl_xor(v, off);
  return v;
}

// row permutation within each batch's 1024 rows
__device__ __forceinline__ int map_row(int t, int mode) {
  switch (mode) {
    case 1: return 1023 - t;                                   // flip
    case 2: return ((t & 31) << 5) | (t >> 5);                 // 32x32 transpose
    case 3: { int u = 1023 - t; return ((u & 31) << 5) | (u >> 5); } // perm(flip)
    case 4: return 1023 - (((t & 31) << 5) | (t >> 5));        // flip(perm)
    default: return t;
  }
}

// ---------------- LN on input (B,192,H,W) -> xs (B*N,192) ----------------
__global__ __launch_bounds__(256) void ln_in_kernel(
    const float* __restrict__ x, const float* __restrict__ g,
    const float* __restrict__ b, float* __restrict__ xs)
{
  int wave = threadIdx.x >> 6;
  int lane = threadIdx.x & 63;
  int r = blockIdx.x * 4 + wave;          // b*1024 + n
  int bb = r >> 10, n = r & 1023;
  const float* xb = x + (size_t)bb * DM * L + n;
  float v[3];
  float s = 0.f, s2 = 0.f;
  #pragma unroll
  for (int j = 0; j < 3; ++j) {
    int c = lane + j * 64;
    v[j] = xb[(size_t)c * L];
    s += v[j]; s2 += v[j] * v[j];
  }
  s = wave_sum(s); s2 = wave_sum(s2);
  float mean = s * (1.f / DM);
  float var  = s2 * (1.f / DM) - mean * mean;
  float rstd = rsqrtf(var + 1e-5f);
  float* xo = xs + (size_t)r * DM;
  #pragma unroll
  for (int j = 0; j < 3; ++j) {
    int c = lane + j * 64;
    xo[c] = (v[j] - mean) * rstd * g[c] + b[c];
  }
}

// ---------------- generic fp32 GEMM: C[m, coff+n] = act(permA(m) @ W^T + bias) ----------------
// A: (4096 rows via map_row, K), W: (N,K) row-major, C row stride ldc.
// BM=128, BN=64, BK=16; 256 threads; thread tile 4m x 8n.
__global__ __launch_bounds__(256) void gemm_kernel(
    const float* __restrict__ A, const float* __restrict__ W,
    const float* __restrict__ bias, float* __restrict__ C,
    int N, int K, int ldc, int coff, int permMode, int act)
{
  __shared__ float As[16][132];
  __shared__ float Bs[16][68];
  int tid = threadIdx.x;
  int m0 = blockIdx.x * 128;
  int n0 = blockIdx.y * 64;
  int tm = (tid & 31) * 4;
  int tn = (tid >> 5) * 8;
  float acc[4][8];
  #pragma unroll
  for (int i = 0; i < 4; ++i)
    #pragma unroll
    for (int j = 0; j < 8; ++j) acc[i][j] = 0.f;

  int ar = tid >> 2;            // 0..63
  int kq = (tid & 3) * 4;       // 0,4,8,12

  for (int k0 = 0; k0 < K; k0 += 16) {
    #pragma unroll
    for (int half = 0; half < 2; ++half) {
      int row = m0 + ar + half * 64;
      int mrow = (row & ~1023) | map_row(row & 1023, permMode);
      float4 v = *(const float4*)(A + (size_t)mrow * K + k0 + kq);
      As[kq + 0][ar + half * 64] = v.x;
      As[kq + 1][ar + half * 64] = v.y;
      As[kq + 2][ar + half * 64] = v.z;
      As[kq + 3][ar + half * 64] = v.w;
    }
    {
      int n = n0 + ar;
      float4 v = make_float4(0.f, 0.f, 0.f, 0.f);
      if (n < N) v = *(const float4*)(W + (size_t)n * K + k0 + kq);
      Bs[kq + 0][ar] = v.x;
      Bs[kq + 1][ar] = v.y;
      Bs[kq + 2][ar] = v.z;
      Bs[kq + 3][ar] = v.w;
    }
    __syncthreads();
    #pragma unroll
    for (int kk = 0; kk < 16; ++kk) {
      float4 a  = *(const float4*)&As[kk][tm];
      float4 b0 = *(const float4*)&Bs[kk][tn];
      float4 b1 = *(const float4*)&Bs[kk][tn + 4];
      float av[4] = {a.x, a.y, a.z, a.w};
      float bv[8] = {b0.x, b0.y, b0.z, b0.w, b1.x, b1.y, b1.z, b1.w};
      #pragma unroll
      for (int i = 0; i < 4; ++i)
        #pragma unroll
        for (int j = 0; j < 8; ++j)
          acc[i][j] = fmaf(av[i], bv[j], acc[i][j]);
    }
    __syncthreads();
  }
  #pragma unroll
  for (int i = 0; i < 4; ++i) {
    int m = m0 + tm + i;
    float* crow = C + (size_t)m * ldc + coff;
    #pragma unroll
    for (int j = 0; j < 8; ++j) {
      int n = n0 + tn + j;
      if (n < N) {
        float v = acc[i][j];
        if (bias) v += bias[n];
        if (act == 1) v = 0.5f * v * (1.f + erff(v * 0.70710678118f)); // exact gelu
        crow[n] = v;
      }
    }
  }
}

// ---------------- depthwise causal conv (k=4) + bias + silu ----------------
__global__ __launch_bounds__(256) void conv_silu_kernel(
    const float* __restrict__ xz, const float* __restrict__ cw,
    const float* __restrict__ cb, float* __restrict__ xsm)
{
  int idx = blockIdx.x * 256 + threadIdx.x;   // 16*1024*384 total
  int d = idx % DI;
  int rest = idx / DI;
  int t = rest & 1023;
  int seq = rest >> 10;
  int k = seq >> 2;
  const float* xh = xz + (size_t)seq * L * (2 * DI) + d;
  const float* w = cw + ((size_t)k * DI + d) * 4;
  float acc = cb[k * DI + d];
  #pragma unroll
  for (int j = 0; j < 4; ++j) {
    int tt = t - 3 + j;
    if (tt >= 0) acc = fmaf(w[j], xh[(size_t)tt * (2 * DI)], acc);
  }
  float sig = 1.f / (1.f + __expf(-acc));
  xsm[idx] = acc * sig;
}

// ---------------- dt = softplus(dbl[:, :12] @ Wdt^T + bdt) ----------------
__global__ __launch_bounds__(256) void dt_kernel(
    const float* __restrict__ dbl, const float* __restrict__ Wdt,
    const float* __restrict__ bdt, float* __restrict__ dt)
{
  int idx = blockIdx.x * 256 + threadIdx.x;   // 16*1024*384
  int d = idx % DI;
  int row = idx / DI;        // seq*1024 + t
  int k = row >> 12;
  const float* dl = dbl + (size_t)row * 44;
  const float* w = Wdt + ((size_t)k * DI + d) * DR;
  float acc = bdt[k * DI + d];
  #pragma unroll
  for (int r = 0; r < DR; ++r) acc = fmaf(w[r], dl[r], acc);
  dt[idx] = (acc > 20.f) ? acc : log1pf(__expf(acc));
}

// ---------------- selective scan: lane per (d,s), shfl-reduce over s ----------------
// writes gated y in-place over xsm
__global__ __launch_bounds__(256) void scan_kernel(
    const float* __restrict__ dbl, const float* __restrict__ dt,
    const float* __restrict__ xz, float* __restrict__ xsm,
    const float* __restrict__ Alog, const float* __restrict__ Dp)
{
  int seq = blockIdx.y;
  int k = seq >> 2;
  int tid = threadIdx.x;
  int dl = tid >> 4;                 // 0..15
  int s  = tid & 15;                 // state index
  int d = blockIdx.x * 16 + dl;
  float A  = -__expf(Alog[((size_t)k * DI + d) * DS + s]);
  float Dv = Dp[k * DI + d];
  float h = 0.f;
  const float* dblp = dbl + (size_t)seq * L * 44;
  const float* dtp  = dt  + (size_t)seq * L * DI + d;
  float*       xpp  = xsm + (size_t)seq * L * DI + d;
  const float* zp   = xz  + (size_t)seq * L * (2 * DI) + DI + d;
  for (int t = 0; t < L; ++t) {
    float dtv = dtp[(size_t)t * DI];
    float xv  = xpp[(size_t)t * DI];
    float Bv  = dblp[t * 44 + DR + s];
    float Cv  = dblp[t * 44 + DR + DS + s];
    float dA = __expf(dtv * A);
    h = fmaf(dA, h, dtv * Bv * xv);
    float p = h * Cv;
    p += __shfl_xor(p, 1);
    p += __shfl_xor(p, 2);
    p += __shfl_xor(p, 4);
    p += __shfl_xor(p, 8);
    if (s == 0) {
      float zv = zp[(size_t)t * (2 * DI)];
      float sig = 1.f / (1.f + __expf(-zv));
      xpp[(size_t)t * DI] = (p + Dv * xv) * (zv * sig);
    }
  }
}

// ---------------- final LN + residual, write (B,192,H,W) ----------------
__global__ __launch_bounds__(256) void ln_out_kernel(
    const float* __restrict__ outp, const float* __restrict__ g,
    const float* __restrict__ b, const float* __restrict__ xs,
    float* __restrict__ out)
{
  int wave = threadIdx.x >> 6;
  int lane = threadIdx.x & 63;
  int r = blockIdx.x * 4 + wave;
  int bb = r >> 10, n = r & 1023;
  const float* xr = outp + (size_t)r * DM;
  float v[3];
  float s = 0.f, s2 = 0.f;
  #pragma unroll
  for (int j = 0; j < 3; ++j) {
    int c = lane + j * 64;
    v[j] = xr[c];
    s += v[j]; s2 += v[j] * v[j];
  }
  s = wave_sum(s); s2 = wave_sum(s2);
  float mean = s * (1.f / DM);
  float var  = s2 * (1.f / DM) - mean * mean;
  float rstd = rsqrtf(var + 1e-5f);
  const float* xsr = xs + (size_t)r * DM;
  #pragma unroll
  for (int j = 0; j < 3; ++j) {
    int c = lane + j * 64;
    out[(size_t)bb * DM * L + (size_t)c * L + n] =
        (v[j] - mean) * rstd * g[c] + b[c] + xsr[c];
  }
}

// ---------------- host side ----------------
static inline void gemm(const float* A, const float* W, const float* bias, float* C,
                        int N, int K, int ldc, int coff, int perm, int act,
                        hipStream_t s) {
  dim3 grid(ROWS / 128, (N + 63) / 64);
  gemm_kernel<<<grid, 256, 0, s>>>(A, W, bias, C, N, K, ldc, coff, perm, act);
}

extern "C" void kernel_launch(void* const* d_in, const int* in_sizes, int n_in,
                              void* d_out, int out_size, void* d_ws, size_t ws_size,
                              hipStream_t stream) {
  (void)in_sizes; (void)n_in; (void)out_size; (void)ws_size;
  const float* x        = (const float*)d_in[0];
  const float* norm_g   = (const float*)d_in[1];
  const float* norm_b   = (const float*)d_in[2];
  const float* in_w     = (const float*)d_in[3];
  const float* in_b     = (const float*)d_in[4];
  const float* m_in_w   = (const float*)d_in[5];
  const float* m_conv_w = (const float*)d_in[6];
  const float* m_conv_b = (const float*)d_in[7];
  const float* m_xp_w   = (const float*)d_in[8];
  const float* m_dt_w   = (const float*)d_in[9];
  const float* m_dt_b   = (const float*)d_in[10];
  const float* m_Alog   = (const float*)d_in[11];
  const float* m_D      = (const float*)d_in[12];
  const float* m_out_w  = (const float*)d_in[13];
  const float* f_w1     = (const float*)d_in[14];
  const float* f_b1     = (const float*)d_in[15];
  const float* f_w2     = (const float*)d_in[16];
  const float* f_b2     = (const float*)d_in[17];
  const float* o_w      = (const float*)d_in[18];
  const float* o_b      = (const float*)d_in[19];
  const float* on_g     = (const float*)d_in[20];
  const float* on_b     = (const float*)d_in[21];
  float* out = (float*)d_out;

  float* ws   = (float*)d_ws;
  float* xs   = ws;                        // 786432
  float* xp   = xs  + 786432;              // 786432
  float* xz   = xp  + 786432;              // 16*1024*768 = 12582912
  float* xsm  = xz  + 12582912;            // 16*1024*384 = 6291456
  float* dbl  = xsm + 6291456;             // 16*1024*44  = 720896
  float* dtb  = dbl + 720896;              // 6291456
  // xz is dead after scan_kernel -> alias tail buffers into it
  float* fused = xz;                       // 4096*768 = 3145728
  float* hdn   = xz + 3145728;             // 4096*384 = 1572864
  float* h2    = hdn + 1572864;            // 4096*192 = 786432
  float* outp  = h2 + 786432;              // 786432

  // 1) input layernorm + transpose
  ln_in_kernel<<<1024, 256, 0, stream>>>(x, norm_g, norm_b, xs);
  // 2) xp = xs @ in_w^T + in_b
  gemm(xs, in_w, in_b, xp, DM, DM, DM, 0, 0, 0, stream);
  // 3) per-direction xz_k = perm_k(xp) @ Win_k^T   (gathers seq permutation)
  for (int k = 0; k < 4; ++k)
    gemm(xp, m_in_w + (size_t)k * 2 * DI * DM, nullptr,
         xz + (size_t)k * ROWS * 2 * DI, 2 * DI, DM, 2 * DI, 0, k, 0, stream);
  // 4) depthwise causal conv + silu  -> xsm
  conv_silu_kernel<<<(16 * L * DI) / 256, 256, 0, stream>>>(xz, m_conv_w, m_conv_b, xsm);
  // 5) dbl_k = xsm_k @ Wxp_k^T  (N=44)
  for (int k = 0; k < 4; ++k)
    gemm(xsm + (size_t)k * ROWS * DI, m_xp_w + (size_t)k * 44 * DI, nullptr,
         dbl + (size_t)k * ROWS * 44, 44, DI, 44, 0, 0, 0, stream);
  // 6) dt = softplus(dbl[:,:12] @ Wdt^T + bdt)
  dt_kernel<<<(16 * L * DI) / 256, 256, 0, stream>>>(dbl, m_dt_w, m_dt_b, dtb);
  // 7) selective scan + D skip + silu(z) gate, in-place into xsm
  scan_kernel<<<dim3(DI / 16, 16), 256, 0, stream>>>(dbl, dtb, xz, xsm, m_Alog, m_D);
  // 8) out-proj per direction, gather with inverse permutation, scatter into fused cols
  static const int outmap[4] = {0, 1, 2, 4};
  for (int k = 0; k < 4; ++k)
    gemm(xsm + (size_t)k * ROWS * DI, m_out_w + (size_t)k * DM * DI, nullptr,
         fused, DM, DI, 4 * DM, k * DM, outmap[k], 0, stream);
  // 9) MLP
  gemm(fused, f_w1, f_b1, hdn, 2 * DM, 4 * DM, 2 * DM, 0, 0, 1, stream); // gelu
  gemm(hdn, f_w2, f_b2, h2, DM, 2 * DM, DM, 0, 0, 0, stream);
  // 10) out proj
  gemm(h2, o_w, o_b, outp, DM, DM, DM, 0, 0, 0, stream);
  // 11) final LN + residual + transpose to (B,192,H,W)
  ln_out_kernel<<<1024, 256, 0, stream>>>(outp, on_g, on_b, xs, out);
}

// Round 2
// 782.031 us; speedup vs baseline: 2.0642x; 2.0642x over previous
//
#include <hip/hip_runtime.h>
#include <cstddef>

#define DM 192
#define DI 384
#define DS 16
#define DR 12
#define L 1024
#define ROWS 4096   // B*N = 4*1024
#define TC 64       // scan time-chunk

// ---------------- helpers ----------------
__device__ __forceinline__ float wave_sum(float v) {
  #pragma unroll
  for (int off = 32; off > 0; off >>= 1) v += __shfl_xor(v, off);
  return v;
}

// row permutation within each batch's 1024 rows
__device__ __forceinline__ int map_row(int t, int mode) {
  switch (mode) {
    case 1: return 1023 - t;                                   // flip
    case 2: return ((t & 31) << 5) | (t >> 5);                 // 32x32 transpose
    case 3: { int u = 1023 - t; return ((u & 31) << 5) | (u >> 5); } // perm(flip)
    case 4: return 1023 - (((t & 31) << 5) | (t >> 5));        // flip(perm)
    default: return t;
  }
}

// ---------------- LN on input (B,192,H,W) -> xs (B*N,192) ----------------
__global__ __launch_bounds__(256) void ln_in_kernel(
    const float* __restrict__ x, const float* __restrict__ g,
    const float* __restrict__ b, float* __restrict__ xs)
{
  int wave = threadIdx.x >> 6;
  int lane = threadIdx.x & 63;
  int r = blockIdx.x * 4 + wave;          // b*1024 + n
  int bb = r >> 10, n = r & 1023;
  const float* xb = x + (size_t)bb * DM * L + n;
  float v[3];
  float s = 0.f, s2 = 0.f;
  #pragma unroll
  for (int j = 0; j < 3; ++j) {
    int c = lane + j * 64;
    v[j] = xb[(size_t)c * L];
    s += v[j]; s2 += v[j] * v[j];
  }
  s = wave_sum(s); s2 = wave_sum(s2);
  float mean = s * (1.f / DM);
  float var  = s2 * (1.f / DM) - mean * mean;
  float rstd = rsqrtf(var + 1e-5f);
  float* xo = xs + (size_t)r * DM;
  #pragma unroll
  for (int j = 0; j < 3; ++j) {
    int c = lane + j * 64;
    xo[c] = (v[j] - mean) * rstd * g[c] + b[c];
  }
}

// ---------------- generic fp32 GEMM with gridDim.z batching ----------------
// C[z][m, coff+n] = act(permA_z(m) @ W_z^T + bias)
// A: (4096 rows via map_row, K), W: (N,K) row-major, C row stride ldc.
// BM=128, BN=64, BK=16; 256 threads; thread tile 4m x 8n.
__global__ __launch_bounds__(256) void gemm_kernel(
    const float* __restrict__ A, const float* __restrict__ W,
    const float* __restrict__ bias, float* __restrict__ C,
    int N, int K, int ldc, int coff, int4 perm, int act,
    long astride, long wstride, long cstride, int coffstride)
{
  __shared__ float As[16][132];
  __shared__ float Bs[16][68];
  int z = blockIdx.z;
  A += (size_t)z * astride;
  W += (size_t)z * wstride;
  C += (size_t)z * cstride;
  int permMode = (z == 0) ? perm.x : (z == 1) ? perm.y : (z == 2) ? perm.z : perm.w;
  int co = coff + z * coffstride;

  int tid = threadIdx.x;
  int m0 = blockIdx.x * 128;
  int n0 = blockIdx.y * 64;
  int tm = (tid & 31) * 4;
  int tn = (tid >> 5) * 8;
  float acc[4][8];
  #pragma unroll
  for (int i = 0; i < 4; ++i)
    #pragma unroll
    for (int j = 0; j < 8; ++j) acc[i][j] = 0.f;

  int ar = tid >> 2;            // 0..63
  int kq = (tid & 3) * 4;       // 0,4,8,12

  for (int k0 = 0; k0 < K; k0 += 16) {
    #pragma unroll
    for (int half = 0; half < 2; ++half) {
      int row = m0 + ar + half * 64;
      int mrow = (row & ~1023) | map_row(row & 1023, permMode);
      float4 v = *(const float4*)(A + (size_t)mrow * K + k0 + kq);
      As[kq + 0][ar + half * 64] = v.x;
      As[kq + 1][ar + half * 64] = v.y;
      As[kq + 2][ar + half * 64] = v.z;
      As[kq + 3][ar + half * 64] = v.w;
    }
    {
      int n = n0 + ar;
      float4 v = make_float4(0.f, 0.f, 0.f, 0.f);
      if (n < N) v = *(const float4*)(W + (size_t)n * K + k0 + kq);
      Bs[kq + 0][ar] = v.x;
      Bs[kq + 1][ar] = v.y;
      Bs[kq + 2][ar] = v.z;
      Bs[kq + 3][ar] = v.w;
    }
    __syncthreads();
    #pragma unroll
    for (int kk = 0; kk < 16; ++kk) {
      float4 a  = *(const float4*)&As[kk][tm];
      float4 b0 = *(const float4*)&Bs[kk][tn];
      float4 b1 = *(const float4*)&Bs[kk][tn + 4];
      float av[4] = {a.x, a.y, a.z, a.w};
      float bv[8] = {b0.x, b0.y, b0.z, b0.w, b1.x, b1.y, b1.z, b1.w};
      #pragma unroll
      for (int i = 0; i < 4; ++i)
        #pragma unroll
        for (int j = 0; j < 8; ++j)
          acc[i][j] = fmaf(av[i], bv[j], acc[i][j]);
    }
    __syncthreads();
  }
  #pragma unroll
  for (int i = 0; i < 4; ++i) {
    int m = m0 + tm + i;
    float* crow = C + (size_t)m * ldc + co;
    #pragma unroll
    for (int j = 0; j < 8; ++j) {
      int n = n0 + tn + j;
      if (n < N) {
        float v = acc[i][j];
        if (bias) v += bias[n];
        if (act == 1) v = 0.5f * v * (1.f + erff(v * 0.70710678118f)); // exact gelu
        crow[n] = v;
      }
    }
  }
}

// ---------------- depthwise causal conv (k=4) + bias + silu ----------------
__global__ __launch_bounds__(256) void conv_silu_kernel(
    const float* __restrict__ xz, const float* __restrict__ cw,
    const float* __restrict__ cb, float* __restrict__ xsm)
{
  int idx = blockIdx.x * 256 + threadIdx.x;   // 16*1024*384 total
  int d = idx % DI;
  int rest = idx / DI;
  int t = rest & 1023;
  int seq = rest >> 10;
  int k = seq >> 2;
  const float* xh = xz + (size_t)seq * L * (2 * DI) + d;
  const float* w = cw + ((size_t)k * DI + d) * 4;
  float acc = cb[k * DI + d];
  #pragma unroll
  for (int j = 0; j < 4; ++j) {
    int tt = t - 3 + j;
    if (tt >= 0) acc = fmaf(w[j], xh[(size_t)tt * (2 * DI)], acc);
  }
  float sig = 1.f / (1.f + __expf(-acc));
  xsm[idx] = acc * sig;
}

// ---------------- dt = softplus(dbl[:, :12] @ Wdt^T + bdt) ----------------
__global__ __launch_bounds__(256) void dt_kernel(
    const float* __restrict__ dbl, const float* __restrict__ Wdt,
    const float* __restrict__ bdt, float* __restrict__ dt)
{
  int idx = blockIdx.x * 256 + threadIdx.x;   // 16*1024*384
  int d = idx % DI;
  int row = idx / DI;        // seq*1024 + t
  int k = row >> 12;
  const float* dl = dbl + (size_t)row * 44;
  const float* w = Wdt + ((size_t)k * DI + d) * DR;
  float acc = bdt[k * DI + d];
  #pragma unroll
  for (int r = 0; r < DR; ++r) acc = fmaf(w[r], dl[r], acc);
  dt[idx] = (acc > 20.f) ? acc : log1pf(__expf(acc));
}

// ---------------- selective scan v2: chunked LDS staging, double-buffered ----------------
// block = 128 threads = 8 channels x 16 states; grid (DI/8, 16 seqs) = 768 blocks
// writes gated y in-place over xsm
__global__ __launch_bounds__(128) void scan_kernel(
    const float* __restrict__ dbl, const float* __restrict__ dt,
    const float* __restrict__ xz, float* __restrict__ xsm,
    const float* __restrict__ Alog, const float* __restrict__ Dp)
{
  __shared__ __align__(16) float sX [2][TC][8];
  __shared__ __align__(16) float sDt[2][TC][8];
  __shared__ __align__(16) float sZ [2][TC][8];
  __shared__ __align__(16) float sBC[2][TC][32];
  __shared__ __align__(16) float sY [TC][8];

  int seq = blockIdx.y;
  int k = seq >> 2;
  int d0 = blockIdx.x * 8;
  int tid = threadIdx.x;
  int dl = tid >> 4;      // 0..7
  int s  = tid & 15;      // state index

  float A  = -__expf(Alog[(size_t)(k * DI + d0 + dl) * DS + s]);
  float Dv = Dp[k * DI + d0 + dl];

  const float* xbase  = xsm + (size_t)seq * L * DI + d0;
  const float* dtbase = dt  + (size_t)seq * L * DI + d0;
  const float* zbase  = xz  + (size_t)seq * L * (2 * DI) + DI + d0;
  const float* bcbase = dbl + (size_t)seq * L * 44 + 12;
  float*       ybase  = xsm + (size_t)seq * L * DI + d0;

  int st_t = tid >> 1;          // 0..63
  int st_g = (tid & 1) * 4;     // 0 or 4

  float4 rX, rDt, rZ, rBC[4];
  // ---- load + store chunk 0 ----
  rX  = *(const float4*)(xbase  + (size_t)st_t * DI + st_g);
  rDt = *(const float4*)(dtbase + (size_t)st_t * DI + st_g);
  rZ  = *(const float4*)(zbase  + (size_t)st_t * (2 * DI) + st_g);
  #pragma unroll
  for (int j = 0; j < 4; ++j) {
    int idx = tid + j * 128;
    int tt = idx >> 3, q = (idx & 7) * 4;
    rBC[j] = *(const float4*)(bcbase + (size_t)tt * 44 + q);
  }
  *(float4*)&sX [0][st_t][st_g] = rX;
  *(float4*)&sDt[0][st_t][st_g] = rDt;
  *(float4*)&sZ [0][st_t][st_g] = rZ;
  #pragma unroll
  for (int j = 0; j < 4; ++j) {
    int idx = tid + j * 128;
    int tt = idx >> 3, q = (idx & 7) * 4;
    *(float4*)&sBC[0][tt][q] = rBC[j];
  }
  __syncthreads();

  float h = 0.f;
  for (int c = 0; c < L / TC; ++c) {
    int cur = c & 1;
    // ---- prefetch chunk c+1 into registers ----
    if (c + 1 < L / TC) {
      int tg = (c + 1) * TC + st_t;
      rX  = *(const float4*)(xbase  + (size_t)tg * DI + st_g);
      rDt = *(const float4*)(dtbase + (size_t)tg * DI + st_g);
      rZ  = *(const float4*)(zbase  + (size_t)tg * (2 * DI) + st_g);
      #pragma unroll
      for (int j = 0; j < 4; ++j) {
        int idx = tid + j * 128;
        int tt = (c + 1) * TC + (idx >> 3), q = (idx & 7) * 4;
        rBC[j] = *(const float4*)(bcbase + (size_t)tt * 44 + q);
      }
    }
    // ---- compute chunk c from LDS ----
    #pragma unroll 8
    for (int t = 0; t < TC; ++t) {
      float dtv = sDt[cur][t][dl];
      float xv  = sX [cur][t][dl];
      float Bv  = sBC[cur][t][s];
      float Cv  = sBC[cur][t][16 + s];
      float dA = __expf(dtv * A);
      h = fmaf(dA, h, dtv * Bv * xv);
      float p = h * Cv;
      p += __shfl_xor(p, 1);
      p += __shfl_xor(p, 2);
      p += __shfl_xor(p, 4);
      p += __shfl_xor(p, 8);
      if (s == 0) sY[t][dl] = fmaf(Dv, xv, p);
    }
    __syncthreads();
    // ---- gated coalesced writeout ----
    {
      float4 y = *(float4*)&sY[st_t][st_g];
      float4 zv = *(float4*)&sZ[cur][st_t][st_g];
      y.x *= zv.x / (1.f + __expf(-zv.x));
      y.y *= zv.y / (1.f + __expf(-zv.y));
      y.z *= zv.z / (1.f + __expf(-zv.z));
      y.w *= zv.w / (1.f + __expf(-zv.w));
      *(float4*)(ybase + (size_t)(c * TC + st_t) * DI + st_g) = y;
    }
    // ---- stage prefetched regs into next buffer ----
    if (c + 1 < L / TC) {
      int nxt = cur ^ 1;
      *(float4*)&sX [nxt][st_t][st_g] = rX;
      *(float4*)&sDt[nxt][st_t][st_g] = rDt;
      *(float4*)&sZ [nxt][st_t][st_g] = rZ;
      #pragma unroll
      for (int j = 0; j < 4; ++j) {
        int idx = tid + j * 128;
        int tt = idx >> 3, q = (idx & 7) * 4;
        *(float4*)&sBC[nxt][tt][q] = rBC[j];
      }
    }
    __syncthreads();
  }
}

// ---------------- final LN + residual, write (B,192,H,W) ----------------
__global__ __launch_bounds__(256) void ln_out_kernel(
    const float* __restrict__ outp, const float* __restrict__ g,
    const float* __restrict__ b, const float* __restrict__ xs,
    float* __restrict__ out)
{
  int wave = threadIdx.x >> 6;
  int lane = threadIdx.x & 63;
  int r = blockIdx.x * 4 + wave;
  int bb = r >> 10, n = r & 1023;
  const float* xr = outp + (size_t)r * DM;
  float v[3];
  float s = 0.f, s2 = 0.f;
  #pragma unroll
  for (int j = 0; j < 3; ++j) {
    int c = lane + j * 64;
    v[j] = xr[c];
    s += v[j]; s2 += v[j] * v[j];
  }
  s = wave_sum(s); s2 = wave_sum(s2);
  float mean = s * (1.f / DM);
  float var  = s2 * (1.f / DM) - mean * mean;
  float rstd = rsqrtf(var + 1e-5f);
  const float* xsr = xs + (size_t)r * DM;
  #pragma unroll
  for (int j = 0; j < 3; ++j) {
    int c = lane + j * 64;
    out[(size_t)bb * DM * L + (size_t)c * L + n] =
        (v[j] - mean) * rstd * g[c] + b[c] + xsr[c];
  }
}

// ---------------- host side ----------------
static inline void gemm(const float* A, const float* W, const float* bias, float* C,
                        int N, int K, int ldc, int coff, int4 perm, int act,
                        int nz, long astride, long wstride, long cstride, int coffstride,
                        hipStream_t s) {
  dim3 grid(ROWS / 128, (N + 63) / 64, nz);
  gemm_kernel<<<grid, 256, 0, s>>>(A, W, bias, C, N, K, ldc, coff, perm, act,
                                   astride, wstride, cstride, coffstride);
}

extern "C" void kernel_launch(void* const* d_in, const int* in_sizes, int n_in,
                              void* d_out, int out_size, void* d_ws, size_t ws_size,
                              hipStream_t stream) {
  (void)in_sizes; (void)n_in; (void)out_size; (void)ws_size;
  const float* x        = (const float*)d_in[0];
  const float* norm_g   = (const float*)d_in[1];
  const float* norm_b   = (const float*)d_in[2];
  const float* in_w     = (const float*)d_in[3];
  const float* in_b     = (const float*)d_in[4];
  const float* m_in_w   = (const float*)d_in[5];
  const float* m_conv_w = (const float*)d_in[6];
  const float* m_conv_b = (const float*)d_in[7];
  const float* m_xp_w   = (const float*)d_in[8];
  const float* m_dt_w   = (const float*)d_in[9];
  const float* m_dt_b   = (const float*)d_in[10];
  const float* m_Alog   = (const float*)d_in[11];
  const float* m_D      = (const float*)d_in[12];
  const float* m_out_w  = (const float*)d_in[13];
  const float* f_w1     = (const float*)d_in[14];
  const float* f_b1     = (const float*)d_in[15];
  const float* f_w2     = (const float*)d_in[16];
  const float* f_b2     = (const float*)d_in[17];
  const float* o_w      = (const float*)d_in[18];
  const float* o_b      = (const float*)d_in[19];
  const float* on_g     = (const float*)d_in[20];
  const float* on_b     = (const float*)d_in[21];
  float* out = (float*)d_out;

  float* ws   = (float*)d_ws;
  float* xs   = ws;                        // 786432
  float* xp   = xs  + 786432;              // 786432
  float* xz   = xp  + 786432;              // 16*1024*768 = 12582912
  float* xsm  = xz  + 12582912;            // 16*1024*384 = 6291456
  float* dbl  = xsm + 6291456;             // 16*1024*44  = 720896
  float* dtb  = dbl + 720896;              // 6291456
  // xz is dead after scan_kernel -> alias tail buffers into it
  float* fused = xz;                       // 4096*768 = 3145728
  float* hdn   = xz + 3145728;             // 4096*384 = 1572864
  float* h2    = hdn + 1572864;            // 4096*192 = 786432
  float* outp  = h2 + 786432;              // 786432

  int4 p0 = make_int4(0, 0, 0, 0);
  int4 pfwd = make_int4(0, 1, 2, 3);
  int4 pinv = make_int4(0, 1, 2, 4);

  // 1) input layernorm + transpose
  ln_in_kernel<<<1024, 256, 0, stream>>>(x, norm_g, norm_b, xs);
  // 2) xp = xs @ in_w^T + in_b
  gemm(xs, in_w, in_b, xp, DM, DM, DM, 0, p0, 0, 1, 0, 0, 0, 0, stream);
  // 3) xz_k = perm_k(xp) @ Win_k^T  — one dispatch, z = direction
  gemm(xp, m_in_w, nullptr, xz, 2 * DI, DM, 2 * DI, 0, pfwd, 0,
       4, 0, (long)2 * DI * DM, (long)ROWS * 2 * DI, 0, stream);
  // 4) depthwise causal conv + silu  -> xsm
  conv_silu_kernel<<<(16 * L * DI) / 256, 256, 0, stream>>>(xz, m_conv_w, m_conv_b, xsm);
  // 5) dbl_k = xsm_k @ Wxp_k^T  (N=44) — one dispatch
  gemm(xsm, m_xp_w, nullptr, dbl, 44, DI, 44, 0, p0, 0,
       4, (long)ROWS * DI, (long)44 * DI, (long)ROWS * 44, 0, stream);
  // 6) dt = softplus(dbl[:,:12] @ Wdt^T + bdt)
  dt_kernel<<<(16 * L * DI) / 256, 256, 0, stream>>>(dbl, m_dt_w, m_dt_b, dtb);
  // 7) selective scan + D skip + silu(z) gate, in-place into xsm
  scan_kernel<<<dim3(DI / 8, 16), 128, 0, stream>>>(dbl, dtb, xz, xsm, m_Alog, m_D);
  // 8) out-proj per direction (gather inverse perm), scatter into fused cols — one dispatch
  gemm(xsm, m_out_w, nullptr, fused, DM, DI, 4 * DM, 0, pinv, 0,
       4, (long)ROWS * DI, (long)DM * DI, 0, DM, stream);
  // 9) MLP
  gemm(fused, f_w1, f_b1, hdn, 2 * DM, 4 * DM, 2 * DM, 0, p0, 1, 1, 0, 0, 0, 0, stream); // gelu
  gemm(hdn, f_w2, f_b2, h2, DM, 2 * DM, DM, 0, p0, 0, 1, 0, 0, 0, 0, stream);
  // 10) out proj
  gemm(h2, o_w, o_b, outp, DM, DM, DM, 0, p0, 0, 1, 0, 0, 0, 0, stream);
  // 11) final LN + residual + transpose to (B,192,H,W)
  ln_out_kernel<<<1024, 256, 0, stream>>>(outp, on_g, on_b, xs, out);
}

// Round 3
// 699.164 us; speedup vs baseline: 2.3089x; 1.1185x over previous
//
#include <hip/hip_runtime.h>
#include <cstddef>

#define DM 192
#define DI 384
#define DS 16
#define DR 12
#define L 1024
#define ROWS 4096   // B*N = 4*1024
#define SEG 8       // time segments for two-pass scan
#define ST  128     // steps per segment

// ---------------- helpers ----------------
__device__ __forceinline__ float wave_sum(float v) {
  #pragma unroll
  for (int off = 32; off > 0; off >>= 1) v += __shfl_xor(v, off);
  return v;
}

// row permutation within each batch's 1024 rows
__device__ __forceinline__ int map_row(int t, int mode) {
  switch (mode) {
    case 1: return 1023 - t;                                   // flip
    case 2: return ((t & 31) << 5) | (t >> 5);                 // 32x32 transpose
    case 3: { int u = 1023 - t; return ((u & 31) << 5) | (u >> 5); } // perm(flip)
    case 4: return 1023 - (((t & 31) << 5) | (t >> 5));        // flip(perm)
    default: return t;
  }
}

// ---------------- LN on input (B,192,H,W) -> xs (B*N,192) ----------------
__global__ __launch_bounds__(256) void ln_in_kernel(
    const float* __restrict__ x, const float* __restrict__ g,
    const float* __restrict__ b, float* __restrict__ xs)
{
  int wave = threadIdx.x >> 6;
  int lane = threadIdx.x & 63;
  int r = blockIdx.x * 4 + wave;          // b*1024 + n
  int bb = r >> 10, n = r & 1023;
  const float* xb = x + (size_t)bb * DM * L + n;
  float v[3];
  float s = 0.f, s2 = 0.f;
  #pragma unroll
  for (int j = 0; j < 3; ++j) {
    int c = lane + j * 64;
    v[j] = xb[(size_t)c * L];
    s += v[j]; s2 += v[j] * v[j];
  }
  s = wave_sum(s); s2 = wave_sum(s2);
  float mean = s * (1.f / DM);
  float var  = s2 * (1.f / DM) - mean * mean;
  float rstd = rsqrtf(var + 1e-5f);
  float* xo = xs + (size_t)r * DM;
  #pragma unroll
  for (int j = 0; j < 3; ++j) {
    int c = lane + j * 64;
    xo[c] = (v[j] - mean) * rstd * g[c] + b[c];
  }
}

// ---------------- generic fp32 GEMM with gridDim.z batching ----------------
__global__ __launch_bounds__(256) void gemm_kernel(
    const float* __restrict__ A, const float* __restrict__ W,
    const float* __restrict__ bias, float* __restrict__ C,
    int N, int K, int ldc, int coff, int4 perm, int act,
    long astride, long wstride, long cstride, int coffstride)
{
  __shared__ float As[16][132];
  __shared__ float Bs[16][68];
  int z = blockIdx.z;
  A += (size_t)z * astride;
  W += (size_t)z * wstride;
  C += (size_t)z * cstride;
  int permMode = (z == 0) ? perm.x : (z == 1) ? perm.y : (z == 2) ? perm.z : perm.w;
  int co = coff + z * coffstride;

  int tid = threadIdx.x;
  int m0 = blockIdx.x * 128;
  int n0 = blockIdx.y * 64;
  int tm = (tid & 31) * 4;
  int tn = (tid >> 5) * 8;
  float acc[4][8];
  #pragma unroll
  for (int i = 0; i < 4; ++i)
    #pragma unroll
    for (int j = 0; j < 8; ++j) acc[i][j] = 0.f;

  int ar = tid >> 2;            // 0..63
  int kq = (tid & 3) * 4;       // 0,4,8,12

  for (int k0 = 0; k0 < K; k0 += 16) {
    #pragma unroll
    for (int half = 0; half < 2; ++half) {
      int row = m0 + ar + half * 64;
      int mrow = (row & ~1023) | map_row(row & 1023, permMode);
      float4 v = *(const float4*)(A + (size_t)mrow * K + k0 + kq);
      As[kq + 0][ar + half * 64] = v.x;
      As[kq + 1][ar + half * 64] = v.y;
      As[kq + 2][ar + half * 64] = v.z;
      As[kq + 3][ar + half * 64] = v.w;
    }
    {
      int n = n0 + ar;
      float4 v = make_float4(0.f, 0.f, 0.f, 0.f);
      if (n < N) v = *(const float4*)(W + (size_t)n * K + k0 + kq);
      Bs[kq + 0][ar] = v.x;
      Bs[kq + 1][ar] = v.y;
      Bs[kq + 2][ar] = v.z;
      Bs[kq + 3][ar] = v.w;
    }
    __syncthreads();
    #pragma unroll
    for (int kk = 0; kk < 16; ++kk) {
      float4 a  = *(const float4*)&As[kk][tm];
      float4 b0 = *(const float4*)&Bs[kk][tn];
      float4 b1 = *(const float4*)&Bs[kk][tn + 4];
      float av[4] = {a.x, a.y, a.z, a.w};
      float bv[8] = {b0.x, b0.y, b0.z, b0.w, b1.x, b1.y, b1.z, b1.w};
      #pragma unroll
      for (int i = 0; i < 4; ++i)
        #pragma unroll
        for (int j = 0; j < 8; ++j)
          acc[i][j] = fmaf(av[i], bv[j], acc[i][j]);
    }
    __syncthreads();
  }
  #pragma unroll
  for (int i = 0; i < 4; ++i) {
    int m = m0 + tm + i;
    float* crow = C + (size_t)m * ldc + co;
    #pragma unroll
    for (int j = 0; j < 8; ++j) {
      int n = n0 + tn + j;
      if (n < N) {
        float v = acc[i][j];
        if (bias) v += bias[n];
        if (act == 1) v = 0.5f * v * (1.f + erff(v * 0.70710678118f)); // exact gelu
        crow[n] = v;
      }
    }
  }
}

// ---------------- depthwise causal conv (k=4) + bias + silu ----------------
__global__ __launch_bounds__(256) void conv_silu_kernel(
    const float* __restrict__ xz, const float* __restrict__ cw,
    const float* __restrict__ cb, float* __restrict__ xsm)
{
  int idx = blockIdx.x * 256 + threadIdx.x;   // 16*1024*384 total
  int d = idx % DI;
  int rest = idx / DI;
  int t = rest & 1023;
  int seq = rest >> 10;
  int k = seq >> 2;
  const float* xh = xz + (size_t)seq * L * (2 * DI) + d;
  const float* w = cw + ((size_t)k * DI + d) * 4;
  float acc = cb[k * DI + d];
  #pragma unroll
  for (int j = 0; j < 4; ++j) {
    int tt = t - 3 + j;
    if (tt >= 0) acc = fmaf(w[j], xh[(size_t)tt * (2 * DI)], acc);
  }
  float sig = 1.f / (1.f + __expf(-acc));
  xsm[idx] = acc * sig;
}

// ---------------- dt = softplus(dbl[:, :12] @ Wdt^T + bdt) ----------------
__global__ __launch_bounds__(256) void dt_kernel(
    const float* __restrict__ dbl, const float* __restrict__ Wdt,
    const float* __restrict__ bdt, float* __restrict__ dt)
{
  int idx = blockIdx.x * 256 + threadIdx.x;   // 16*1024*384
  int d = idx % DI;
  int row = idx / DI;        // seq*1024 + t
  int k = row >> 12;
  const float* dl = dbl + (size_t)row * 44;
  const float* w = Wdt + ((size_t)k * DI + d) * DR;
  float acc = bdt[k * DI + d];
  #pragma unroll
  for (int r = 0; r < DR; ++r) acc = fmaf(w[r], dl[r], acc);
  dt[idx] = (acc > 20.f) ? acc : log1pf(__expf(acc));
}

// ---------------- scan pass 1: per-segment partial scan from h=0 ----------------
// grid (DI/16, 16 seqs, SEG); block 256 = 16 ch x 16 states
// stores h_end per (seq,seg,d,s) and dt-sum per (seq,seg,d)
__global__ __launch_bounds__(256) void scan_pass1(
    const float* __restrict__ dbl, const float* __restrict__ dt,
    const float* __restrict__ xsm, const float* __restrict__ Alog,
    float* __restrict__ hseg, float* __restrict__ Sseg)
{
  __shared__ __align__(16) float sDt[ST][16];
  __shared__ __align__(16) float sX [ST][16];
  __shared__ __align__(16) float sB [ST][16];
  int d0  = blockIdx.x * 16;
  int seq = blockIdx.y;
  int g   = blockIdx.z;
  int k   = seq >> 2;
  int tid = threadIdx.x;
  int dl = tid >> 4, s = tid & 15;

  const float* dtbase = dt  + ((size_t)seq * L + g * ST) * DI + d0;
  const float* xbase  = xsm + ((size_t)seq * L + g * ST) * DI + d0;
  const float* bbase  = dbl + ((size_t)seq * L + g * ST) * 44 + 12;

  #pragma unroll
  for (int j = 0; j < 2; ++j) {
    int idx = tid + j * 256;
    int t = idx >> 2, c4 = (idx & 3) * 4;
    *(float4*)&sDt[t][c4] = *(const float4*)(dtbase + (size_t)t * DI + c4);
    *(float4*)&sX [t][c4] = *(const float4*)(xbase  + (size_t)t * DI + c4);
    *(float4*)&sB [t][c4] = *(const float4*)(bbase  + (size_t)t * 44 + c4);
  }
  float A = -__expf(Alog[((size_t)k * DI + d0 + dl) * DS + s]);
  __syncthreads();

  float h = 0.f, sdt = 0.f;
  #pragma unroll 8
  for (int t = 0; t < ST; ++t) {
    float dtv = sDt[t][dl];
    float dA = __expf(dtv * A);
    h = fmaf(dA, h, dtv * sB[t][s] * sX[t][dl]);
    sdt += dtv;
  }
  hseg[(((size_t)seq * SEG + g) * DI + d0 + dl) * DS + s] = h;
  if (s == 0) Sseg[((size_t)seq * SEG + g) * DI + d0 + dl] = sdt;
}

// ---------------- scan pass 2: closed-form init correction + full scan + gate ----------------
// grid (DI/16, 16 seqs, SEG); block 256 = 16 ch x 16 states; writes y in place over xsm
__global__ __launch_bounds__(256) void scan_pass2(
    const float* __restrict__ dbl, const float* __restrict__ dt,
    const float* __restrict__ xz, float* __restrict__ xsm,
    const float* __restrict__ Alog, const float* __restrict__ Dp,
    const float* __restrict__ hseg, const float* __restrict__ Sseg)
{
  __shared__ __align__(16) float sDt[ST][16];
  __shared__ __align__(16) float sX [ST][16];
  __shared__ __align__(16) float sBC[ST][32];
  __shared__ __align__(16) float sY [ST][16];
  int d0  = blockIdx.x * 16;
  int seq = blockIdx.y;
  int g   = blockIdx.z;
  int k   = seq >> 2;
  int tid = threadIdx.x;
  int dl = tid >> 4, s = tid & 15;

  const float* dtbase = dt  + ((size_t)seq * L + g * ST) * DI + d0;
  const float* xbase  = xsm + ((size_t)seq * L + g * ST) * DI + d0;
  const float* bcbase = dbl + ((size_t)seq * L + g * ST) * 44 + 12;
  const float* zbase  = xz  + ((size_t)seq * L + g * ST) * (2 * DI) + DI + d0;
  float*       ybase  = xsm + ((size_t)seq * L + g * ST) * DI + d0;

  // stage segment into LDS
  #pragma unroll
  for (int j = 0; j < 2; ++j) {
    int idx = tid + j * 256;
    int t = idx >> 2, c4 = (idx & 3) * 4;
    *(float4*)&sDt[t][c4] = *(const float4*)(dtbase + (size_t)t * DI + c4);
    *(float4*)&sX [t][c4] = *(const float4*)(xbase  + (size_t)t * DI + c4);
  }
  #pragma unroll
  for (int j = 0; j < 4; ++j) {
    int idx = tid + j * 256;
    int t = idx >> 3, q = (idx & 7) * 4;
    *(float4*)&sBC[t][q] = *(const float4*)(bcbase + (size_t)t * 44 + q);
  }

  float A  = -__expf(Alog[((size_t)k * DI + d0 + dl) * DS + s]);
  float Dv = Dp[k * DI + d0 + dl];

  // closed-form initial state: H = sum_j h_j * exp(A * sum_{k>j} S_k)
  float h = 0.f;
  {
    float cumS = 0.f;
    for (int j = g - 1; j >= 0; --j) {
      float hj = hseg[(((size_t)seq * SEG + j) * DI + d0 + dl) * DS + s];
      float Sj = Sseg[((size_t)seq * SEG + j) * DI + d0 + dl];
      h = fmaf(hj, __expf(A * cumS), h);
      cumS += Sj;
    }
  }
  __syncthreads();

  #pragma unroll 4
  for (int t = 0; t < ST; ++t) {
    float dtv = sDt[t][dl];
    float xv  = sX[t][dl];
    float dA = __expf(dtv * A);
    h = fmaf(dA, h, dtv * sBC[t][s] * xv);
    float p = h * sBC[t][16 + s];
    p += __shfl_xor(p, 1);
    p += __shfl_xor(p, 2);
    p += __shfl_xor(p, 4);
    p += __shfl_xor(p, 8);
    if (s == 0) sY[t][dl] = fmaf(Dv, xv, p);
  }
  __syncthreads();

  // gated coalesced writeout
  #pragma unroll
  for (int j = 0; j < 2; ++j) {
    int idx = tid + j * 256;
    int t = idx >> 2, c4 = (idx & 3) * 4;
    float4 y  = *(float4*)&sY[t][c4];
    float4 zv = *(const float4*)(zbase + (size_t)t * (2 * DI) + c4);
    y.x *= zv.x / (1.f + __expf(-zv.x));
    y.y *= zv.y / (1.f + __expf(-zv.y));
    y.z *= zv.z / (1.f + __expf(-zv.z));
    y.w *= zv.w / (1.f + __expf(-zv.w));
    *(float4*)(ybase + (size_t)t * DI + c4) = y;
  }
}

// ---------------- final LN + residual, write (B,192,H,W) ----------------
__global__ __launch_bounds__(256) void ln_out_kernel(
    const float* __restrict__ outp, const float* __restrict__ g,
    const float* __restrict__ b, const float* __restrict__ xs,
    float* __restrict__ out)
{
  int wave = threadIdx.x >> 6;
  int lane = threadIdx.x & 63;
  int r = blockIdx.x * 4 + wave;
  int bb = r >> 10, n = r & 1023;
  const float* xr = outp + (size_t)r * DM;
  float v[3];
  float s = 0.f, s2 = 0.f;
  #pragma unroll
  for (int j = 0; j < 3; ++j) {
    int c = lane + j * 64;
    v[j] = xr[c];
    s += v[j]; s2 += v[j] * v[j];
  }
  s = wave_sum(s); s2 = wave_sum(s2);
  float mean = s * (1.f / DM);
  float var  = s2 * (1.f / DM) - mean * mean;
  float rstd = rsqrtf(var + 1e-5f);
  const float* xsr = xs + (size_t)r * DM;
  #pragma unroll
  for (int j = 0; j < 3; ++j) {
    int c = lane + j * 64;
    out[(size_t)bb * DM * L + (size_t)c * L + n] =
        (v[j] - mean) * rstd * g[c] + b[c] + xsr[c];
  }
}

// ---------------- host side ----------------
static inline void gemm(const float* A, const float* W, const float* bias, float* C,
                        int N, int K, int ldc, int coff, int4 perm, int act,
                        int nz, long astride, long wstride, long cstride, int coffstride,
                        hipStream_t s) {
  dim3 grid(ROWS / 128, (N + 63) / 64, nz);
  gemm_kernel<<<grid, 256, 0, s>>>(A, W, bias, C, N, K, ldc, coff, perm, act,
                                   astride, wstride, cstride, coffstride);
}

extern "C" void kernel_launch(void* const* d_in, const int* in_sizes, int n_in,
                              void* d_out, int out_size, void* d_ws, size_t ws_size,
                              hipStream_t stream) {
  (void)in_sizes; (void)n_in; (void)out_size; (void)ws_size;
  const float* x        = (const float*)d_in[0];
  const float* norm_g   = (const float*)d_in[1];
  const float* norm_b   = (const float*)d_in[2];
  const float* in_w     = (const float*)d_in[3];
  const float* in_b     = (const float*)d_in[4];
  const float* m_in_w   = (const float*)d_in[5];
  const float* m_conv_w = (const float*)d_in[6];
  const float* m_conv_b = (const float*)d_in[7];
  const float* m_xp_w   = (const float*)d_in[8];
  const float* m_dt_w   = (const float*)d_in[9];
  const float* m_dt_b   = (const float*)d_in[10];
  const float* m_Alog   = (const float*)d_in[11];
  const float* m_D      = (const float*)d_in[12];
  const float* m_out_w  = (const float*)d_in[13];
  const float* f_w1     = (const float*)d_in[14];
  const float* f_b1     = (const float*)d_in[15];
  const float* f_w2     = (const float*)d_in[16];
  const float* f_b2     = (const float*)d_in[17];
  const float* o_w      = (const float*)d_in[18];
  const float* o_b      = (const float*)d_in[19];
  const float* on_g     = (const float*)d_in[20];
  const float* on_b     = (const float*)d_in[21];
  float* out = (float*)d_out;

  float* ws   = (float*)d_ws;
  float* xs   = ws;                        // 786432
  float* xp   = xs  + 786432;              // 786432 (dead after xz-GEMM -> reused as hseg)
  float* xz   = xp  + 786432;              // 16*1024*768 = 12582912
  float* xsm  = xz  + 12582912;            // 16*1024*384 = 6291456
  float* dbl  = xsm + 6291456;             // 16*1024*44  = 720896
  float* dtb  = dbl + 720896;              // 6291456
  float* Sseg = dtb + 6291456;             // 16*8*384 = 49152
  float* hseg = xp;                        // 16*8*384*16 = 786432 (exact fit)
  // xz is dead after scan -> alias tail buffers into it
  float* fused = xz;                       // 4096*768 = 3145728
  float* hdn   = xz + 3145728;             // 4096*384 = 1572864
  float* h2    = hdn + 1572864;            // 4096*192 = 786432
  float* outp  = h2 + 786432;              // 786432

  int4 p0 = make_int4(0, 0, 0, 0);
  int4 pfwd = make_int4(0, 1, 2, 3);
  int4 pinv = make_int4(0, 1, 2, 4);

  // 1) input layernorm + transpose
  ln_in_kernel<<<1024, 256, 0, stream>>>(x, norm_g, norm_b, xs);
  // 2) xp = xs @ in_w^T + in_b
  gemm(xs, in_w, in_b, xp, DM, DM, DM, 0, p0, 0, 1, 0, 0, 0, 0, stream);
  // 3) xz_k = perm_k(xp) @ Win_k^T  — one dispatch, z = direction
  gemm(xp, m_in_w, nullptr, xz, 2 * DI, DM, 2 * DI, 0, pfwd, 0,
       4, 0, (long)2 * DI * DM, (long)ROWS * 2 * DI, 0, stream);
  // 4) depthwise causal conv + silu  -> xsm
  conv_silu_kernel<<<(16 * L * DI) / 256, 256, 0, stream>>>(xz, m_conv_w, m_conv_b, xsm);
  // 5) dbl_k = xsm_k @ Wxp_k^T  (N=44) — one dispatch
  gemm(xsm, m_xp_w, nullptr, dbl, 44, DI, 44, 0, p0, 0,
       4, (long)ROWS * DI, (long)44 * DI, (long)ROWS * 44, 0, stream);
  // 6) dt = softplus(dbl[:,:12] @ Wdt^T + bdt)
  dt_kernel<<<(16 * L * DI) / 256, 256, 0, stream>>>(dbl, m_dt_w, m_dt_b, dtb);
  // 7) two-pass time-segmented selective scan (+ D skip + silu(z) gate), in place in xsm
  scan_pass1<<<dim3(DI / 16, 16, SEG), 256, 0, stream>>>(dbl, dtb, xsm, m_Alog, hseg, Sseg);
  scan_pass2<<<dim3(DI / 16, 16, SEG), 256, 0, stream>>>(dbl, dtb, xz, xsm, m_Alog, m_D, hseg, Sseg);
  // 8) out-proj per direction (gather inverse perm), scatter into fused cols — one dispatch
  gemm(xsm, m_out_w, nullptr, fused, DM, DI, 4 * DM, 0, pinv, 0,
       4, (long)ROWS * DI, (long)DM * DI, 0, DM, stream);
  // 9) MLP
  gemm(fused, f_w1, f_b1, hdn, 2 * DM, 4 * DM, 2 * DM, 0, p0, 1, 1, 0, 0, 0, 0, stream); // gelu
  gemm(hdn, f_w2, f_b2, h2, DM, 2 * DM, DM, 0, p0, 0, 1, 0, 0, 0, 0, stream);
  // 10) out proj
  gemm(h2, o_w, o_b, outp, DM, DM, DM, 0, p0, 0, 1, 0, 0, 0, 0, stream);
  // 11) final LN + residual + transpose to (B,192,H,W)
  ln_out_kernel<<<1024, 256, 0, stream>>>(outp, on_g, on_b, xs, out);
}

// Round 4
// 448.701 us; speedup vs baseline: 3.5977x; 1.5582x over previous
//
#include <hip/hip_runtime.h>
#include <cstddef>

#define DM 192
#define DI 384
#define DS 16
#define DR 12
#define L 1024
#define ROWS 4096   // B*N = 4*1024
#define SEG 8       // time segments for two-pass scan
#define ST  128     // steps per segment

typedef short bf16x8 __attribute__((ext_vector_type(8)));
typedef float f32x4  __attribute__((ext_vector_type(4)));

// ---------------- helpers ----------------
__device__ __forceinline__ float wave_sum(float v) {
  #pragma unroll
  for (int off = 32; off > 0; off >>= 1) v += __shfl_xor(v, off);
  return v;
}

__device__ __forceinline__ short f2bf(float x) {   // fp32 -> bf16 RNE
  unsigned u = __float_as_uint(x);
  u += 0x7fffu + ((u >> 16) & 1u);
  return (short)(u >> 16);
}

// row permutation within each batch's 1024 rows
__device__ __forceinline__ int map_row(int t, int mode) {
  switch (mode) {
    case 1: return 1023 - t;                                   // flip
    case 2: return ((t & 31) << 5) | (t >> 5);                 // 32x32 transpose
    case 3: { int u = 1023 - t; return ((u & 31) << 5) | (u >> 5); } // perm(flip)
    case 4: return 1023 - (((t & 31) << 5) | (t >> 5));        // flip(perm)
    default: return t;
  }
}

// ---------------- LN on input (B,192,H,W) -> xs (B*N,192) ----------------
__global__ __launch_bounds__(256) void ln_in_kernel(
    const float* __restrict__ x, const float* __restrict__ g,
    const float* __restrict__ b, float* __restrict__ xs)
{
  int wave = threadIdx.x >> 6;
  int lane = threadIdx.x & 63;
  int r = blockIdx.x * 4 + wave;          // b*1024 + n
  int bb = r >> 10, n = r & 1023;
  const float* xb = x + (size_t)bb * DM * L + n;
  float v[3];
  float s = 0.f, s2 = 0.f;
  #pragma unroll
  for (int j = 0; j < 3; ++j) {
    int c = lane + j * 64;
    v[j] = xb[(size_t)c * L];
    s += v[j]; s2 += v[j] * v[j];
  }
  s = wave_sum(s); s2 = wave_sum(s2);
  float mean = s * (1.f / DM);
  float var  = s2 * (1.f / DM) - mean * mean;
  float rstd = rsqrtf(var + 1e-5f);
  float* xo = xs + (size_t)r * DM;
  #pragma unroll
  for (int j = 0; j < 3; ++j) {
    int c = lane + j * 64;
    xo[c] = (v[j] - mean) * rstd * g[c] + b[c];
  }
}

// ---------------- bf16 MFMA GEMM with gridDim.z batching ----------------
// C[z][m, coff+n] = act(permA_z(m) @ W_z^T + bias); inputs fp32, math bf16 MFMA.
// BM=128, BN=64, BK=32; 256 threads = 4 waves (2x2), wave tile 64x32.
__global__ __launch_bounds__(256) void gemm_kernel(
    const float* __restrict__ A, const float* __restrict__ W,
    const float* __restrict__ bias, float* __restrict__ C,
    int N, int K, int ldc, int coff, int4 perm, int act,
    long astride, long wstride, long cstride, int coffstride)
{
  __shared__ __align__(16) short As[128][40];   // stride 40 shorts = 80 B
  __shared__ __align__(16) short Bs[64][40];

  int z = blockIdx.z;
  A += (size_t)z * astride;
  W += (size_t)z * wstride;
  C += (size_t)z * cstride;
  int permMode = (z == 0) ? perm.x : (z == 1) ? perm.y : (z == 2) ? perm.z : perm.w;
  int co = coff + z * coffstride;

  int tid = threadIdx.x;
  int m0 = blockIdx.x * 128;
  int n0 = blockIdx.y * 64;

  // staging coords
  int abr = tid >> 1;               // A row in tile 0..127
  int akq = (tid & 1) * 16;         // 0 or 16
  int arow = m0 + abr;
  int amrow = (arow & ~1023) | map_row(arow & 1023, permMode);
  const float* ap = A + (size_t)amrow * K + akq;
  int bn  = tid >> 2;               // B row (n) 0..63
  int bkq = (tid & 3) * 8;
  const float* wp = W + (size_t)(n0 + bn) * K + bkq;
  bool bok = (n0 + bn) < N;

  // compute coords
  int lane = tid & 63;
  int w = tid >> 6, wm = w >> 1, wn = w & 1;
  int lm = lane & 15, lq = lane >> 4;

  f32x4 acc[4][2];
  #pragma unroll
  for (int i = 0; i < 4; ++i)
    #pragma unroll
    for (int j = 0; j < 2; ++j) acc[i][j] = (f32x4){0.f, 0.f, 0.f, 0.f};

  for (int k0 = 0; k0 < K; k0 += 32) {
    // ---- stage A tile (128x32) fp32 -> bf16 ----
    {
      float4 v0 = *(const float4*)(ap + k0);
      float4 v1 = *(const float4*)(ap + k0 + 4);
      float4 v2 = *(const float4*)(ap + k0 + 8);
      float4 v3 = *(const float4*)(ap + k0 + 12);
      bf16x8 t0 = {f2bf(v0.x), f2bf(v0.y), f2bf(v0.z), f2bf(v0.w),
                   f2bf(v1.x), f2bf(v1.y), f2bf(v1.z), f2bf(v1.w)};
      bf16x8 t1 = {f2bf(v2.x), f2bf(v2.y), f2bf(v2.z), f2bf(v2.w),
                   f2bf(v3.x), f2bf(v3.y), f2bf(v3.z), f2bf(v3.w)};
      *(bf16x8*)&As[abr][akq]     = t0;
      *(bf16x8*)&As[abr][akq + 8] = t1;
    }
    // ---- stage B tile (64x32) ----
    {
      float4 u0 = make_float4(0.f, 0.f, 0.f, 0.f), u1 = u0;
      if (bok) {
        u0 = *(const float4*)(wp + k0);
        u1 = *(const float4*)(wp + k0 + 4);
      }
      bf16x8 t = {f2bf(u0.x), f2bf(u0.y), f2bf(u0.z), f2bf(u0.w),
                  f2bf(u1.x), f2bf(u1.y), f2bf(u1.z), f2bf(u1.w)};
      *(bf16x8*)&Bs[bn][bkq] = t;
    }
    __syncthreads();
    // ---- MFMA ----
    bf16x8 fa[4], fb[2];
    #pragma unroll
    for (int i = 0; i < 4; ++i)
      fa[i] = *(const bf16x8*)&As[wm * 64 + i * 16 + lm][lq * 8];
    #pragma unroll
    for (int j = 0; j < 2; ++j)
      fb[j] = *(const bf16x8*)&Bs[wn * 32 + j * 16 + lm][lq * 8];
    #pragma unroll
    for (int i = 0; i < 4; ++i)
      #pragma unroll
      for (int j = 0; j < 2; ++j)
        acc[i][j] = __builtin_amdgcn_mfma_f32_16x16x32_bf16(fa[i], fb[j], acc[i][j], 0, 0, 0);
    __syncthreads();
  }

  // ---- epilogue: C/D layout col=lane&15, row=quad*4+reg ----
  #pragma unroll
  for (int i = 0; i < 4; ++i) {
    #pragma unroll
    for (int r = 0; r < 4; ++r) {
      int row = m0 + wm * 64 + i * 16 + lq * 4 + r;
      float* crow = C + (size_t)row * ldc + co;
      #pragma unroll
      for (int j = 0; j < 2; ++j) {
        int n = n0 + wn * 32 + j * 16 + lm;
        if (n < N) {
          float v = acc[i][j][r];
          if (bias) v += bias[n];
          if (act == 1) v = 0.5f * v * (1.f + erff(v * 0.70710678118f)); // exact gelu
          crow[n] = v;
        }
      }
    }
  }
}

// ---------------- depthwise causal conv (k=4) + bias + silu ----------------
__global__ __launch_bounds__(256) void conv_silu_kernel(
    const float* __restrict__ xz, const float* __restrict__ cw,
    const float* __restrict__ cb, float* __restrict__ xsm)
{
  int idx = blockIdx.x * 256 + threadIdx.x;   // 16*1024*384 total
  int d = idx % DI;
  int rest = idx / DI;
  int t = rest & 1023;
  int seq = rest >> 10;
  int k = seq >> 2;
  const float* xh = xz + (size_t)seq * L * (2 * DI) + d;
  const float* w = cw + ((size_t)k * DI + d) * 4;
  float acc = cb[k * DI + d];
  #pragma unroll
  for (int j = 0; j < 4; ++j) {
    int tt = t - 3 + j;
    if (tt >= 0) acc = fmaf(w[j], xh[(size_t)tt * (2 * DI)], acc);
  }
  float sig = 1.f / (1.f + __expf(-acc));
  xsm[idx] = acc * sig;
}

// ---------------- dt = softplus(dbl[:, :12] @ Wdt^T + bdt) ----------------
__global__ __launch_bounds__(256) void dt_kernel(
    const float* __restrict__ dbl, const float* __restrict__ Wdt,
    const float* __restrict__ bdt, float* __restrict__ dt)
{
  int idx = blockIdx.x * 256 + threadIdx.x;   // 16*1024*384
  int d = idx % DI;
  int row = idx / DI;        // seq*1024 + t
  int k = row >> 12;
  const float* dl = dbl + (size_t)row * 44;
  const float* w = Wdt + ((size_t)k * DI + d) * DR;
  float acc = bdt[k * DI + d];
  #pragma unroll
  for (int r = 0; r < DR; ++r) acc = fmaf(w[r], dl[r], acc);
  dt[idx] = (acc > 20.f) ? acc : log1pf(__expf(acc));
}

// ---------------- scan pass 1: per-segment partial scan from h=0 ----------------
__global__ __launch_bounds__(256) void scan_pass1(
    const float* __restrict__ dbl, const float* __restrict__ dt,
    const float* __restrict__ xsm, const float* __restrict__ Alog,
    float* __restrict__ hseg, float* __restrict__ Sseg)
{
  __shared__ __align__(16) float sDt[ST][16];
  __shared__ __align__(16) float sX [ST][16];
  __shared__ __align__(16) float sB [ST][16];
  int d0  = blockIdx.x * 16;
  int seq = blockIdx.y;
  int g   = blockIdx.z;
  int k   = seq >> 2;
  int tid = threadIdx.x;
  int dl = tid >> 4, s = tid & 15;

  const float* dtbase = dt  + ((size_t)seq * L + g * ST) * DI + d0;
  const float* xbase  = xsm + ((size_t)seq * L + g * ST) * DI + d0;
  const float* bbase  = dbl + ((size_t)seq * L + g * ST) * 44 + 12;

  #pragma unroll
  for (int j = 0; j < 2; ++j) {
    int idx = tid + j * 256;
    int t = idx >> 2, c4 = (idx & 3) * 4;
    *(float4*)&sDt[t][c4] = *(const float4*)(dtbase + (size_t)t * DI + c4);
    *(float4*)&sX [t][c4] = *(const float4*)(xbase  + (size_t)t * DI + c4);
    *(float4*)&sB [t][c4] = *(const float4*)(bbase  + (size_t)t * 44 + c4);
  }
  float A = -__expf(Alog[((size_t)k * DI + d0 + dl) * DS + s]);
  __syncthreads();

  float h = 0.f, sdt = 0.f;
  #pragma unroll 8
  for (int t = 0; t < ST; ++t) {
    float dtv = sDt[t][dl];
    float dA = __expf(dtv * A);
    h = fmaf(dA, h, dtv * sB[t][s] * sX[t][dl]);
    sdt += dtv;
  }
  hseg[(((size_t)seq * SEG + g) * DI + d0 + dl) * DS + s] = h;
  if (s == 0) Sseg[((size_t)seq * SEG + g) * DI + d0 + dl] = sdt;
}

// ---------------- scan pass 2: closed-form init correction + full scan + gate ----------------
__global__ __launch_bounds__(256) void scan_pass2(
    const float* __restrict__ dbl, const float* __restrict__ dt,
    const float* __restrict__ xz, float* __restrict__ xsm,
    const float* __restrict__ Alog, const float* __restrict__ Dp,
    const float* __restrict__ hseg, const float* __restrict__ Sseg)
{
  __shared__ __align__(16) float sDt[ST][16];
  __shared__ __align__(16) float sX [ST][16];
  __shared__ __align__(16) float sBC[ST][32];
  __shared__ __align__(16) float sY [ST][16];
  int d0  = blockIdx.x * 16;
  int seq = blockIdx.y;
  int g   = blockIdx.z;
  int k   = seq >> 2;
  int tid = threadIdx.x;
  int dl = tid >> 4, s = tid & 15;

  const float* dtbase = dt  + ((size_t)seq * L + g * ST) * DI + d0;
  const float* xbase  = xsm + ((size_t)seq * L + g * ST) * DI + d0;
  const float* bcbase = dbl + ((size_t)seq * L + g * ST) * 44 + 12;
  const float* zbase  = xz  + ((size_t)seq * L + g * ST) * (2 * DI) + DI + d0;
  float*       ybase  = xsm + ((size_t)seq * L + g * ST) * DI + d0;

  #pragma unroll
  for (int j = 0; j < 2; ++j) {
    int idx = tid + j * 256;
    int t = idx >> 2, c4 = (idx & 3) * 4;
    *(float4*)&sDt[t][c4] = *(const float4*)(dtbase + (size_t)t * DI + c4);
    *(float4*)&sX [t][c4] = *(const float4*)(xbase  + (size_t)t * DI + c4);
  }
  #pragma unroll
  for (int j = 0; j < 4; ++j) {
    int idx = tid + j * 256;
    int t = idx >> 3, q = (idx & 7) * 4;
    *(float4*)&sBC[t][q] = *(const float4*)(bcbase + (size_t)t * 44 + q);
  }

  float A  = -__expf(Alog[((size_t)k * DI + d0 + dl) * DS + s]);
  float Dv = Dp[k * DI + d0 + dl];

  float h = 0.f;
  {
    float cumS = 0.f;
    for (int j = g - 1; j >= 0; --j) {
      float hj = hseg[(((size_t)seq * SEG + j) * DI + d0 + dl) * DS + s];
      float Sj = Sseg[((size_t)seq * SEG + j) * DI + d0 + dl];
      h = fmaf(hj, __expf(A * cumS), h);
      cumS += Sj;
    }
  }
  __syncthreads();

  #pragma unroll 4
  for (int t = 0; t < ST; ++t) {
    float dtv = sDt[t][dl];
    float xv  = sX[t][dl];
    float dA = __expf(dtv * A);
    h = fmaf(dA, h, dtv * sBC[t][s] * xv);
    float p = h * sBC[t][16 + s];
    p += __shfl_xor(p, 1);
    p += __shfl_xor(p, 2);
    p += __shfl_xor(p, 4);
    p += __shfl_xor(p, 8);
    if (s == 0) sY[t][dl] = fmaf(Dv, xv, p);
  }
  __syncthreads();

  #pragma unroll
  for (int j = 0; j < 2; ++j) {
    int idx = tid + j * 256;
    int t = idx >> 2, c4 = (idx & 3) * 4;
    float4 y  = *(float4*)&sY[t][c4];
    float4 zv = *(const float4*)(zbase + (size_t)t * (2 * DI) + c4);
    y.x *= zv.x / (1.f + __expf(-zv.x));
    y.y *= zv.y / (1.f + __expf(-zv.y));
    y.z *= zv.z / (1.f + __expf(-zv.z));
    y.w *= zv.w / (1.f + __expf(-zv.w));
    *(float4*)(ybase + (size_t)t * DI + c4) = y;
  }
}

// ---------------- final LN + residual, write (B,192,H,W) ----------------
__global__ __launch_bounds__(256) void ln_out_kernel(
    const float* __restrict__ outp, const float* __restrict__ g,
    const float* __restrict__ b, const float* __restrict__ xs,
    float* __restrict__ out)
{
  int wave = threadIdx.x >> 6;
  int lane = threadIdx.x & 63;
  int r = blockIdx.x * 4 + wave;
  int bb = r >> 10, n = r & 1023;
  const float* xr = outp + (size_t)r * DM;
  float v[3];
  float s = 0.f, s2 = 0.f;
  #pragma unroll
  for (int j = 0; j < 3; ++j) {
    int c = lane + j * 64;
    v[j] = xr[c];
    s += v[j]; s2 += v[j] * v[j];
  }
  s = wave_sum(s); s2 = wave_sum(s2);
  float mean = s * (1.f / DM);
  float var  = s2 * (1.f / DM) - mean * mean;
  float rstd = rsqrtf(var + 1e-5f);
  const float* xsr = xs + (size_t)r * DM;
  #pragma unroll
  for (int j = 0; j < 3; ++j) {
    int c = lane + j * 64;
    out[(size_t)bb * DM * L + (size_t)c * L + n] =
        (v[j] - mean) * rstd * g[c] + b[c] + xsr[c];
  }
}

// ---------------- host side ----------------
static inline void gemm(const float* A, const float* W, const float* bias, float* C,
                        int N, int K, int ldc, int coff, int4 perm, int act,
                        int nz, long astride, long wstride, long cstride, int coffstride,
                        hipStream_t s) {
  dim3 grid(ROWS / 128, (N + 63) / 64, nz);
  gemm_kernel<<<grid, 256, 0, s>>>(A, W, bias, C, N, K, ldc, coff, perm, act,
                                   astride, wstride, cstride, coffstride);
}

extern "C" void kernel_launch(void* const* d_in, const int* in_sizes, int n_in,
                              void* d_out, int out_size, void* d_ws, size_t ws_size,
                              hipStream_t stream) {
  (void)in_sizes; (void)n_in; (void)out_size; (void)ws_size;
  const float* x        = (const float*)d_in[0];
  const float* norm_g   = (const float*)d_in[1];
  const float* norm_b   = (const float*)d_in[2];
  const float* in_w     = (const float*)d_in[3];
  const float* in_b     = (const float*)d_in[4];
  const float* m_in_w   = (const float*)d_in[5];
  const float* m_conv_w = (const float*)d_in[6];
  const float* m_conv_b = (const float*)d_in[7];
  const float* m_xp_w   = (const float*)d_in[8];
  const float* m_dt_w   = (const float*)d_in[9];
  const float* m_dt_b   = (const float*)d_in[10];
  const float* m_Alog   = (const float*)d_in[11];
  const float* m_D      = (const float*)d_in[12];
  const float* m_out_w  = (const float*)d_in[13];
  const float* f_w1     = (const float*)d_in[14];
  const float* f_b1     = (const float*)d_in[15];
  const float* f_w2     = (const float*)d_in[16];
  const float* f_b2     = (const float*)d_in[17];
  const float* o_w      = (const float*)d_in[18];
  const float* o_b      = (const float*)d_in[19];
  const float* on_g     = (const float*)d_in[20];
  const float* on_b     = (const float*)d_in[21];
  float* out = (float*)d_out;

  float* ws   = (float*)d_ws;
  float* xs   = ws;                        // 786432
  float* xp   = xs  + 786432;              // 786432 (dead after xz-GEMM -> reused as hseg)
  float* xz   = xp  + 786432;              // 16*1024*768 = 12582912
  float* xsm  = xz  + 12582912;            // 16*1024*384 = 6291456
  float* dbl  = xsm + 6291456;             // 16*1024*44  = 720896
  float* dtb  = dbl + 720896;              // 6291456
  float* Sseg = dtb + 6291456;             // 16*8*384 = 49152
  float* hseg = xp;                        // 16*8*384*16 = 786432 (exact fit)
  // xz is dead after scan -> alias tail buffers into it
  float* fused = xz;                       // 4096*768 = 3145728
  float* hdn   = xz + 3145728;             // 4096*384 = 1572864
  float* h2    = hdn + 1572864;            // 4096*192 = 786432
  float* outp  = h2 + 786432;              // 786432

  int4 p0 = make_int4(0, 0, 0, 0);
  int4 pfwd = make_int4(0, 1, 2, 3);
  int4 pinv = make_int4(0, 1, 2, 4);

  // 1) input layernorm + transpose
  ln_in_kernel<<<1024, 256, 0, stream>>>(x, norm_g, norm_b, xs);
  // 2) xp = xs @ in_w^T + in_b
  gemm(xs, in_w, in_b, xp, DM, DM, DM, 0, p0, 0, 1, 0, 0, 0, 0, stream);
  // 3) xz_k = perm_k(xp) @ Win_k^T  — one dispatch, z = direction
  gemm(xp, m_in_w, nullptr, xz, 2 * DI, DM, 2 * DI, 0, pfwd, 0,
       4, 0, (long)2 * DI * DM, (long)ROWS * 2 * DI, 0, stream);
  // 4) depthwise causal conv + silu  -> xsm
  conv_silu_kernel<<<(16 * L * DI) / 256, 256, 0, stream>>>(xz, m_conv_w, m_conv_b, xsm);
  // 5) dbl_k = xsm_k @ Wxp_k^T  (N=44) — one dispatch
  gemm(xsm, m_xp_w, nullptr, dbl, 44, DI, 44, 0, p0, 0,
       4, (long)ROWS * DI, (long)44 * DI, (long)ROWS * 44, 0, stream);
  // 6) dt = softplus(dbl[:,:12] @ Wdt^T + bdt)
  dt_kernel<<<(16 * L * DI) / 256, 256, 0, stream>>>(dbl, m_dt_w, m_dt_b, dtb);
  // 7) two-pass time-segmented selective scan (+ D skip + silu(z) gate), in place in xsm
  scan_pass1<<<dim3(DI / 16, 16, SEG), 256, 0, stream>>>(dbl, dtb, xsm, m_Alog, hseg, Sseg);
  scan_pass2<<<dim3(DI / 16, 16, SEG), 256, 0, stream>>>(dbl, dtb, xz, xsm, m_Alog, m_D, hseg, Sseg);
  // 8) out-proj per direction (gather inverse perm), scatter into fused cols — one dispatch
  gemm(xsm, m_out_w, nullptr, fused, DM, DI, 4 * DM, 0, pinv, 0,
       4, (long)ROWS * DI, (long)DM * DI, 0, DM, stream);
  // 9) MLP
  gemm(fused, f_w1, f_b1, hdn, 2 * DM, 4 * DM, 2 * DM, 0, p0, 1, 1, 0, 0, 0, 0, stream); // gelu
  gemm(hdn, f_w2, f_b2, h2, DM, 2 * DM, DM, 0, p0, 0, 1, 0, 0, 0, 0, stream);
  // 10) out proj
  gemm(h2, o_w, o_b, outp, DM, DM, DM, 0, p0, 0, 1, 0, 0, 0, 0, stream);
  // 11) final LN + residual + transpose to (B,192,H,W)
  ln_out_kernel<<<1024, 256, 0, stream>>>(outp, on_g, on_b, xs, out);
}

// Round 5
// 436.419 us; speedup vs baseline: 3.6990x; 1.0281x over previous
//
#include <hip/hip_runtime.h>
#include <cstddef>

#define DM 192
#define DI 384
#define DS 16
#define DR 12
#define L 1024
#define ROWS 4096   // B*N = 4*1024
#define SEG 8       // time segments for two-pass scan
#define ST  128     // steps per segment

typedef short bf16x8 __attribute__((ext_vector_type(8)));
typedef float f32x4  __attribute__((ext_vector_type(4)));

// ---------------- helpers ----------------
__device__ __forceinline__ float wave_sum(float v) {
  #pragma unroll
  for (int off = 32; off > 0; off >>= 1) v += __shfl_xor(v, off);
  return v;
}

__device__ __forceinline__ short f2bf(float x) {   // fp32 -> bf16 RNE
  unsigned u = __float_as_uint(x);
  u += 0x7fffu + ((u >> 16) & 1u);
  return (short)(u >> 16);
}

// row permutation within each batch's 1024 rows
__device__ __forceinline__ int map_row(int t, int mode) {
  switch (mode) {
    case 1: return 1023 - t;                                   // flip
    case 2: return ((t & 31) << 5) | (t >> 5);                 // 32x32 transpose
    case 3: { int u = 1023 - t; return ((u & 31) << 5) | (u >> 5); } // perm(flip)
    case 4: return 1023 - (((t & 31) << 5) | (t >> 5));        // flip(perm)
    default: return t;
  }
}

// ---------------- LN on input (B,192,H,W) -> xs (B*N,192) ----------------
__global__ __launch_bounds__(256) void ln_in_kernel(
    const float* __restrict__ x, const float* __restrict__ g,
    const float* __restrict__ b, float* __restrict__ xs)
{
  int wave = threadIdx.x >> 6;
  int lane = threadIdx.x & 63;
  int r = blockIdx.x * 4 + wave;          // b*1024 + n
  int bb = r >> 10, n = r & 1023;
  const float* xb = x + (size_t)bb * DM * L + n;
  float v[3];
  float s = 0.f, s2 = 0.f;
  #pragma unroll
  for (int j = 0; j < 3; ++j) {
    int c = lane + j * 64;
    v[j] = xb[(size_t)c * L];
    s += v[j]; s2 += v[j] * v[j];
  }
  s = wave_sum(s); s2 = wave_sum(s2);
  float mean = s * (1.f / DM);
  float var  = s2 * (1.f / DM) - mean * mean;
  float rstd = rsqrtf(var + 1e-5f);
  float* xo = xs + (size_t)r * DM;
  #pragma unroll
  for (int j = 0; j < 3; ++j) {
    int c = lane + j * 64;
    xo[c] = (v[j] - mean) * rstd * g[c] + b[c];
  }
}

// ---------------- bf16 MFMA GEMM with gridDim.z batching ----------------
// C[z][m, coff+n] = act(permA_z(m) @ W_z^T + bias); inputs fp32, math bf16 MFMA.
// BM=128, BN=64, BK=32; 256 threads = 4 waves (2x2), wave tile 64x32.
__global__ __launch_bounds__(256) void gemm_kernel(
    const float* __restrict__ A, const float* __restrict__ W,
    const float* __restrict__ bias, float* __restrict__ C,
    int N, int K, int ldc, int coff, int4 perm, int act,
    long astride, long wstride, long cstride, int coffstride)
{
  __shared__ __align__(16) short As[128][40];   // stride 40 shorts = 80 B
  __shared__ __align__(16) short Bs[64][40];

  int z = blockIdx.z;
  A += (size_t)z * astride;
  W += (size_t)z * wstride;
  C += (size_t)z * cstride;
  int permMode = (z == 0) ? perm.x : (z == 1) ? perm.y : (z == 2) ? perm.z : perm.w;
  int co = coff + z * coffstride;

  int tid = threadIdx.x;
  int m0 = blockIdx.x * 128;
  int n0 = blockIdx.y * 64;

  // staging coords
  int abr = tid >> 1;               // A row in tile 0..127
  int akq = (tid & 1) * 16;         // 0 or 16
  int arow = m0 + abr;
  int amrow = (arow & ~1023) | map_row(arow & 1023, permMode);
  const float* ap = A + (size_t)amrow * K + akq;
  int bn  = tid >> 2;               // B row (n) 0..63
  int bkq = (tid & 3) * 8;
  const float* wp = W + (size_t)(n0 + bn) * K + bkq;
  bool bok = (n0 + bn) < N;

  // compute coords
  int lane = tid & 63;
  int w = tid >> 6, wm = w >> 1, wn = w & 1;
  int lm = lane & 15, lq = lane >> 4;

  f32x4 acc[4][2];
  #pragma unroll
  for (int i = 0; i < 4; ++i)
    #pragma unroll
    for (int j = 0; j < 2; ++j) acc[i][j] = (f32x4){0.f, 0.f, 0.f, 0.f};

  for (int k0 = 0; k0 < K; k0 += 32) {
    // ---- stage A tile (128x32) fp32 -> bf16 ----
    {
      float4 v0 = *(const float4*)(ap + k0);
      float4 v1 = *(const float4*)(ap + k0 + 4);
      float4 v2 = *(const float4*)(ap + k0 + 8);
      float4 v3 = *(const float4*)(ap + k0 + 12);
      bf16x8 t0 = {f2bf(v0.x), f2bf(v0.y), f2bf(v0.z), f2bf(v0.w),
                   f2bf(v1.x), f2bf(v1.y), f2bf(v1.z), f2bf(v1.w)};
      bf16x8 t1 = {f2bf(v2.x), f2bf(v2.y), f2bf(v2.z), f2bf(v2.w),
                   f2bf(v3.x), f2bf(v3.y), f2bf(v3.z), f2bf(v3.w)};
      *(bf16x8*)&As[abr][akq]     = t0;
      *(bf16x8*)&As[abr][akq + 8] = t1;
    }
    // ---- stage B tile (64x32) ----
    {
      float4 u0 = make_float4(0.f, 0.f, 0.f, 0.f), u1 = u0;
      if (bok) {
        u0 = *(const float4*)(wp + k0);
        u1 = *(const float4*)(wp + k0 + 4);
      }
      bf16x8 t = {f2bf(u0.x), f2bf(u0.y), f2bf(u0.z), f2bf(u0.w),
                  f2bf(u1.x), f2bf(u1.y), f2bf(u1.z), f2bf(u1.w)};
      *(bf16x8*)&Bs[bn][bkq] = t;
    }
    __syncthreads();
    // ---- MFMA ----
    bf16x8 fa[4], fb[2];
    #pragma unroll
    for (int i = 0; i < 4; ++i)
      fa[i] = *(const bf16x8*)&As[wm * 64 + i * 16 + lm][lq * 8];
    #pragma unroll
    for (int j = 0; j < 2; ++j)
      fb[j] = *(const bf16x8*)&Bs[wn * 32 + j * 16 + lm][lq * 8];
    #pragma unroll
    for (int i = 0; i < 4; ++i)
      #pragma unroll
      for (int j = 0; j < 2; ++j)
        acc[i][j] = __builtin_amdgcn_mfma_f32_16x16x32_bf16(fa[i], fb[j], acc[i][j], 0, 0, 0);
    __syncthreads();
  }

  // ---- epilogue: C/D layout col=lane&15, row=quad*4+reg ----
  #pragma unroll
  for (int i = 0; i < 4; ++i) {
    #pragma unroll
    for (int r = 0; r < 4; ++r) {
      int row = m0 + wm * 64 + i * 16 + lq * 4 + r;
      float* crow = C + (size_t)row * ldc + co;
      #pragma unroll
      for (int j = 0; j < 2; ++j) {
        int n = n0 + wn * 32 + j * 16 + lm;
        if (n < N) {
          float v = acc[i][j][r];
          if (bias) v += bias[n];
          if (act == 1) v = 0.5f * v * (1.f + erff(v * 0.70710678118f)); // exact gelu
          crow[n] = v;
        }
      }
    }
  }
}

// ---------------- depthwise causal conv (k=4) + bias + silu ----------------
__global__ __launch_bounds__(256) void conv_silu_kernel(
    const float* __restrict__ xz, const float* __restrict__ cw,
    const float* __restrict__ cb, float* __restrict__ xsm)
{
  int idx = blockIdx.x * 256 + threadIdx.x;   // 16*1024*384 total
  int d = idx % DI;
  int rest = idx / DI;
  int t = rest & 1023;
  int seq = rest >> 10;
  int k = seq >> 2;
  const float* xh = xz + (size_t)seq * L * (2 * DI) + d;
  const float* w = cw + ((size_t)k * DI + d) * 4;
  float acc = cb[k * DI + d];
  #pragma unroll
  for (int j = 0; j < 4; ++j) {
    int tt = t - 3 + j;
    if (tt >= 0) acc = fmaf(w[j], xh[(size_t)tt * (2 * DI)], acc);
  }
  float sig = 1.f / (1.f + __expf(-acc));
  xsm[idx] = acc * sig;
}

// ---------------- dt = softplus(dbl[:, :12] @ Wdt^T + bdt) ----------------
__global__ __launch_bounds__(256) void dt_kernel(
    const float* __restrict__ dbl, const float* __restrict__ Wdt,
    const float* __restrict__ bdt, float* __restrict__ dt)
{
  int idx = blockIdx.x * 256 + threadIdx.x;   // 16*1024*384
  int d = idx % DI;
  int row = idx / DI;        // seq*1024 + t
  int k = row >> 12;
  const float* dl = dbl + (size_t)row * 44;
  const float* w = Wdt + ((size_t)k * DI + d) * DR;
  float acc = bdt[k * DI + d];
  #pragma unroll
  for (int r = 0; r < DR; ++r) acc = fmaf(w[r], dl[r], acc);
  dt[idx] = (acc > 20.f) ? acc : log1pf(__expf(acc));
}

// ---------------- scan pass 1: register-state per-segment partial scan ----------------
// block 128 = 2 waves; lane owns one channel, h[16] in registers.
// grid (DI/128, 16 seqs, SEG)
__global__ __launch_bounds__(128) void scan_pass1(
    const float* __restrict__ dbl, const float* __restrict__ dt,
    const float* __restrict__ xsm, const float* __restrict__ Alog,
    float* __restrict__ hseg, float* __restrict__ Sseg)
{
  __shared__ __align__(16) float sB[ST][16];
  int seq = blockIdx.y, g = blockIdx.z, k = seq >> 2;
  int d = blockIdx.x * 128 + threadIdx.x;

  const float* bbase = dbl + ((size_t)seq * L + g * ST) * 44 + 12;
  #pragma unroll
  for (int j = 0; j < 4; ++j) {              // 512 float4 / 128 thr
    int i = threadIdx.x + j * 128;
    int t = i >> 2, q = (i & 3) * 4;
    *(float4*)&sB[t][q] = *(const float4*)(bbase + (size_t)t * 44 + q);
  }
  float A[16];
  const float* alp = Alog + ((size_t)k * DI + d) * DS;
  #pragma unroll
  for (int s = 0; s < 16; ++s) A[s] = -__expf(alp[s]);

  const float* dtp = dt  + ((size_t)seq * L + g * ST) * DI + d;
  const float* xp  = xsm + ((size_t)seq * L + g * ST) * DI + d;
  __syncthreads();

  float h[16];
  #pragma unroll
  for (int s = 0; s < 16; ++s) h[s] = 0.f;
  float sdt = 0.f;
  float dt_n = dtp[0], x_n = xp[0];
  for (int t = 0; t < ST; ++t) {
    float dtv = dt_n, xv = x_n;
    if (t + 1 < ST) {
      dt_n = dtp[(size_t)(t + 1) * DI];
      x_n  = xp [(size_t)(t + 1) * DI];
    }
    float4 b0 = *(const float4*)&sB[t][0];
    float4 b1 = *(const float4*)&sB[t][4];
    float4 b2 = *(const float4*)&sB[t][8];
    float4 b3 = *(const float4*)&sB[t][12];
    float bv[16] = {b0.x,b0.y,b0.z,b0.w, b1.x,b1.y,b1.z,b1.w,
                    b2.x,b2.y,b2.z,b2.w, b3.x,b3.y,b3.z,b3.w};
    float dtx = dtv * xv;
    sdt += dtv;
    #pragma unroll
    for (int s = 0; s < 16; ++s) {
      float dA = __expf(dtv * A[s]);
      h[s] = fmaf(dA, h[s], dtx * bv[s]);
    }
  }
  float* hp = hseg + (((size_t)seq * SEG + g) * DI + d) * DS;
  #pragma unroll
  for (int s = 0; s < 16; ++s) hp[s] = h[s];
  Sseg[((size_t)seq * SEG + g) * DI + d] = sdt;
}

// ---------------- scan pass 2: register-state, closed-form init + scan + gate ----------------
// block 128 = 2 waves; lane owns one channel. grid (DI/128, 16 seqs, SEG)
__global__ __launch_bounds__(128) void scan_pass2(
    const float* __restrict__ dbl, const float* __restrict__ dt,
    const float* __restrict__ xz, float* __restrict__ xsm,
    const float* __restrict__ Alog, const float* __restrict__ Dp,
    const float* __restrict__ hseg, const float* __restrict__ Sseg)
{
  __shared__ __align__(16) float sBC[ST][32];
  int seq = blockIdx.y, g = blockIdx.z, k = seq >> 2;
  int d = blockIdx.x * 128 + threadIdx.x;

  const float* bcbase = dbl + ((size_t)seq * L + g * ST) * 44 + 12;
  #pragma unroll
  for (int j = 0; j < 8; ++j) {              // 1024 float4 / 128 thr
    int i = threadIdx.x + j * 128;
    int t = i >> 3, q = (i & 7) * 4;
    *(float4*)&sBC[t][q] = *(const float4*)(bcbase + (size_t)t * 44 + q);
  }
  float A[16];
  const float* alp = Alog + ((size_t)k * DI + d) * DS;
  #pragma unroll
  for (int s = 0; s < 16; ++s) A[s] = -__expf(alp[s]);
  float Dv = Dp[k * DI + d];

  // closed-form initial state: h = sum_j hseg_j * exp(A * sum_{j<u<g} S_u)
  float h[16];
  #pragma unroll
  for (int s = 0; s < 16; ++s) h[s] = 0.f;
  {
    float cumS = 0.f;
    for (int j = g - 1; j >= 0; --j) {
      const float* hp = hseg + (((size_t)seq * SEG + j) * DI + d) * DS;
      float Sj = Sseg[((size_t)seq * SEG + j) * DI + d];
      #pragma unroll
      for (int s = 0; s < 16; ++s)
        h[s] = fmaf(hp[s], __expf(A[s] * cumS), h[s]);
      cumS += Sj;
    }
  }

  const float* dtp = dt  + ((size_t)seq * L + g * ST) * DI + d;
  const float* zp  = xz  + ((size_t)seq * L + g * ST) * (2 * DI) + DI + d;
  float*       xpp = xsm + ((size_t)seq * L + g * ST) * DI + d;  // x in, y out
  __syncthreads();

  float dt_n = dtp[0], x_n = xpp[0], z_n = zp[0];
  for (int t = 0; t < ST; ++t) {
    float dtv = dt_n, xv = x_n, zv = z_n;
    if (t + 1 < ST) {
      dt_n = dtp[(size_t)(t + 1) * DI];
      x_n  = xpp[(size_t)(t + 1) * DI];
      z_n  = zp [(size_t)(t + 1) * (2 * DI)];
    }
    float4 b0 = *(const float4*)&sBC[t][0];
    float4 b1 = *(const float4*)&sBC[t][4];
    float4 b2 = *(const float4*)&sBC[t][8];
    float4 b3 = *(const float4*)&sBC[t][12];
    float4 c0 = *(const float4*)&sBC[t][16];
    float4 c1 = *(const float4*)&sBC[t][20];
    float4 c2 = *(const float4*)&sBC[t][24];
    float4 c3 = *(const float4*)&sBC[t][28];
    float bv[16] = {b0.x,b0.y,b0.z,b0.w, b1.x,b1.y,b1.z,b1.w,
                    b2.x,b2.y,b2.z,b2.w, b3.x,b3.y,b3.z,b3.w};
    float cv[16] = {c0.x,c0.y,c0.z,c0.w, c1.x,c1.y,c1.z,c1.w,
                    c2.x,c2.y,c2.z,c2.w, c3.x,c3.y,c3.z,c3.w};
    float dtx = dtv * xv;
    float y = 0.f;
    #pragma unroll
    for (int s = 0; s < 16; ++s) {
      float dA = __expf(dtv * A[s]);
      h[s] = fmaf(dA, h[s], dtx * bv[s]);
      y = fmaf(h[s], cv[s], y);
    }
    y = fmaf(Dv, xv, y);
    float sig = 1.f / (1.f + __expf(-zv));
    xpp[(size_t)t * DI] = y * (zv * sig);
  }
}

// ---------------- final LN + residual, write (B,192,H,W) ----------------
__global__ __launch_bounds__(256) void ln_out_kernel(
    const float* __restrict__ outp, const float* __restrict__ g,
    const float* __restrict__ b, const float* __restrict__ xs,
    float* __restrict__ out)
{
  int wave = threadIdx.x >> 6;
  int lane = threadIdx.x & 63;
  int r = blockIdx.x * 4 + wave;
  int bb = r >> 10, n = r & 1023;
  const float* xr = outp + (size_t)r * DM;
  float v[3];
  float s = 0.f, s2 = 0.f;
  #pragma unroll
  for (int j = 0; j < 3; ++j) {
    int c = lane + j * 64;
    v[j] = xr[c];
    s += v[j]; s2 += v[j] * v[j];
  }
  s = wave_sum(s); s2 = wave_sum(s2);
  float mean = s * (1.f / DM);
  float var  = s2 * (1.f / DM) - mean * mean;
  float rstd = rsqrtf(var + 1e-5f);
  const float* xsr = xs + (size_t)r * DM;
  #pragma unroll
  for (int j = 0; j < 3; ++j) {
    int c = lane + j * 64;
    out[(size_t)bb * DM * L + (size_t)c * L + n] =
        (v[j] - mean) * rstd * g[c] + b[c] + xsr[c];
  }
}

// ---------------- host side ----------------
static inline void gemm(const float* A, const float* W, const float* bias, float* C,
                        int N, int K, int ldc, int coff, int4 perm, int act,
                        int nz, long astride, long wstride, long cstride, int coffstride,
                        hipStream_t s) {
  dim3 grid(ROWS / 128, (N + 63) / 64, nz);
  gemm_kernel<<<grid, 256, 0, s>>>(A, W, bias, C, N, K, ldc, coff, perm, act,
                                   astride, wstride, cstride, coffstride);
}

extern "C" void kernel_launch(void* const* d_in, const int* in_sizes, int n_in,
                              void* d_out, int out_size, void* d_ws, size_t ws_size,
                              hipStream_t stream) {
  (void)in_sizes; (void)n_in; (void)out_size; (void)ws_size;
  const float* x        = (const float*)d_in[0];
  const float* norm_g   = (const float*)d_in[1];
  const float* norm_b   = (const float*)d_in[2];
  const float* in_w     = (const float*)d_in[3];
  const float* in_b     = (const float*)d_in[4];
  const float* m_in_w   = (const float*)d_in[5];
  const float* m_conv_w = (const float*)d_in[6];
  const float* m_conv_b = (const float*)d_in[7];
  const float* m_xp_w   = (const float*)d_in[8];
  const float* m_dt_w   = (const float*)d_in[9];
  const float* m_dt_b   = (const float*)d_in[10];
  const float* m_Alog   = (const float*)d_in[11];
  const float* m_D      = (const float*)d_in[12];
  const float* m_out_w  = (const float*)d_in[13];
  const float* f_w1     = (const float*)d_in[14];
  const float* f_b1     = (const float*)d_in[15];
  const float* f_w2     = (const float*)d_in[16];
  const float* f_b2     = (const float*)d_in[17];
  const float* o_w      = (const float*)d_in[18];
  const float* o_b      = (const float*)d_in[19];
  const float* on_g     = (const float*)d_in[20];
  const float* on_b     = (const float*)d_in[21];
  float* out = (float*)d_out;

  float* ws   = (float*)d_ws;
  float* xs   = ws;                        // 786432
  float* xp   = xs  + 786432;              // 786432 (dead after xz-GEMM -> reused as hseg)
  float* xz   = xp  + 786432;              // 16*1024*768 = 12582912
  float* xsm  = xz  + 12582912;            // 16*1024*384 = 6291456
  float* dbl  = xsm + 6291456;             // 16*1024*44  = 720896
  float* dtb  = dbl + 720896;              // 6291456
  float* Sseg = dtb + 6291456;             // 16*8*384 = 49152
  float* hseg = xp;                        // 16*8*384*16 = 786432 (exact fit)
  // xz is dead after scan -> alias tail buffers into it
  float* fused = xz;                       // 4096*768 = 3145728
  float* hdn   = xz + 3145728;             // 4096*384 = 1572864
  float* h2    = hdn + 1572864;            // 4096*192 = 786432
  float* outp  = h2 + 786432;              // 786432

  int4 p0 = make_int4(0, 0, 0, 0);
  int4 pfwd = make_int4(0, 1, 2, 3);
  int4 pinv = make_int4(0, 1, 2, 4);

  // 1) input layernorm + transpose
  ln_in_kernel<<<1024, 256, 0, stream>>>(x, norm_g, norm_b, xs);
  // 2) xp = xs @ in_w^T + in_b
  gemm(xs, in_w, in_b, xp, DM, DM, DM, 0, p0, 0, 1, 0, 0, 0, 0, stream);
  // 3) xz_k = perm_k(xp) @ Win_k^T  — one dispatch, z = direction
  gemm(xp, m_in_w, nullptr, xz, 2 * DI, DM, 2 * DI, 0, pfwd, 0,
       4, 0, (long)2 * DI * DM, (long)ROWS * 2 * DI, 0, stream);
  // 4) depthwise causal conv + silu  -> xsm
  conv_silu_kernel<<<(16 * L * DI) / 256, 256, 0, stream>>>(xz, m_conv_w, m_conv_b, xsm);
  // 5) dbl_k = xsm_k @ Wxp_k^T  (N=44) — one dispatch
  gemm(xsm, m_xp_w, nullptr, dbl, 44, DI, 44, 0, p0, 0,
       4, (long)ROWS * DI, (long)44 * DI, (long)ROWS * 44, 0, stream);
  // 6) dt = softplus(dbl[:,:12] @ Wdt^T + bdt)
  dt_kernel<<<(16 * L * DI) / 256, 256, 0, stream>>>(dbl, m_dt_w, m_dt_b, dtb);
  // 7) two-pass time-segmented selective scan (+ D skip + silu(z) gate), in place in xsm
  scan_pass1<<<dim3(DI / 128, 16, SEG), 128, 0, stream>>>(dbl, dtb, xsm, m_Alog, hseg, Sseg);
  scan_pass2<<<dim3(DI / 128, 16, SEG), 128, 0, stream>>>(dbl, dtb, xz, xsm, m_Alog, m_D, hseg, Sseg);
  // 8) out-proj per direction (gather inverse perm), scatter into fused cols — one dispatch
  gemm(xsm, m_out_w, nullptr, fused, DM, DI, 4 * DM, 0, pinv, 0,
       4, (long)ROWS * DI, (long)DM * DI, 0, DM, stream);
  // 9) MLP
  gemm(fused, f_w1, f_b1, hdn, 2 * DM, 4 * DM, 2 * DM, 0, p0, 1, 1, 0, 0, 0, 0, stream); // gelu
  gemm(hdn, f_w2, f_b2, h2, DM, 2 * DM, DM, 0, p0, 0, 1, 0, 0, 0, 0, stream);
  // 10) out proj
  gemm(h2, o_w, o_b, outp, DM, DM, DM, 0, p0, 0, 1, 0, 0, 0, 0, stream);
  // 11) final LN + residual + transpose to (B,192,H,W)
  ln_out_kernel<<<1024, 256, 0, stream>>>(outp, on_g, on_b, xs, out);
}

// Round 6
// 375.728 us; speedup vs baseline: 4.2965x; 1.1615x over previous
//
#include <hip/hip_runtime.h>
#include <cstddef>

#define DM 192
#define DI 384
#define DS 16
#define DR 12
#define L 1024
#define ROWS 4096   // B*N = 4*1024
#define SEG 8       // time segments for two-pass scan
#define ST  128     // steps per segment

typedef unsigned short ushortx;
typedef short bf16x8 __attribute__((ext_vector_type(8)));
typedef float f32x4  __attribute__((ext_vector_type(4)));

// ---------------- helpers ----------------
__device__ __forceinline__ float wave_sum(float v) {
  #pragma unroll
  for (int off = 32; off > 0; off >>= 1) v += __shfl_xor(v, off);
  return v;
}

__device__ __forceinline__ ushortx f2bf(float x) {   // fp32 -> bf16 RNE
  unsigned u = __float_as_uint(x);
  u += 0x7fffu + ((u >> 16) & 1u);
  return (ushortx)(u >> 16);
}

// row permutation within each batch's 1024 rows
__device__ __forceinline__ int map_row(int t, int mode) {
  switch (mode) {
    case 1: return 1023 - t;                                   // flip
    case 2: return ((t & 31) << 5) | (t >> 5);                 // 32x32 transpose
    case 3: { int u = 1023 - t; return ((u & 31) << 5) | (u >> 5); } // perm(flip)
    case 4: return 1023 - (((t & 31) << 5) | (t >> 5));        // flip(perm)
    default: return t;
  }
}

// ---------------- weight fp32 -> bf16 pre-conversion (7 tensors, one kernel) ----------------
struct WcvtArgs {
  const float* src[7];
  unsigned int off[7];   // dst offset in shorts
  unsigned int n[7];     // element count
};
__global__ __launch_bounds__(256) void wcvt_kernel(WcvtArgs a, ushortx* __restrict__ dst) {
  int w = blockIdx.y;
  int i = (blockIdx.x * 256 + threadIdx.x) * 4;
  if (i >= (int)a.n[w]) return;
  float4 v = *(const float4*)(a.src[w] + i);
  ushort4 o;
  o.x = f2bf(v.x); o.y = f2bf(v.y); o.z = f2bf(v.z); o.w = f2bf(v.w);
  *(ushort4*)(dst + a.off[w] + i) = o;
}

// ---------------- LN on input (B,192,H,W) -> xs fp32 + bf16 ----------------
__global__ __launch_bounds__(256) void ln_in_kernel(
    const float* __restrict__ x, const float* __restrict__ g,
    const float* __restrict__ b, float* __restrict__ xs, ushortx* __restrict__ xs_bf)
{
  int wave = threadIdx.x >> 6;
  int lane = threadIdx.x & 63;
  int r = blockIdx.x * 4 + wave;          // b*1024 + n
  int bb = r >> 10, n = r & 1023;
  const float* xb = x + (size_t)bb * DM * L + n;
  float v[3];
  float s = 0.f, s2 = 0.f;
  #pragma unroll
  for (int j = 0; j < 3; ++j) {
    int c = lane + j * 64;
    v[j] = xb[(size_t)c * L];
    s += v[j]; s2 += v[j] * v[j];
  }
  s = wave_sum(s); s2 = wave_sum(s2);
  float mean = s * (1.f / DM);
  float var  = s2 * (1.f / DM) - mean * mean;
  float rstd = rsqrtf(var + 1e-5f);
  float* xo = xs + (size_t)r * DM;
  ushortx* xob = xs_bf + (size_t)r * DM;
  #pragma unroll
  for (int j = 0; j < 3; ++j) {
    int c = lane + j * 64;
    float val = (v[j] - mean) * rstd * g[c] + b[c];
    xo[c] = val;
    xob[c] = f2bf(val);
  }
}

// ---------------- bf16 MFMA GEMM, all-bf16 operands, gridDim.z batching ----------------
// out = act(permA_z(m) @ W_z^T + bias); C (fp32) and/or Cb (bf16) outputs.
// BM=128, BN=64, BK=32; 256 threads = 4 waves (2x2), wave tile 64x32.
__global__ __launch_bounds__(256) void gemm_kernel(
    const ushortx* __restrict__ A, int lda, const ushortx* __restrict__ W,
    const float* __restrict__ bias, float* __restrict__ C, ushortx* __restrict__ Cb,
    int N, int K, int ldc, int coff, int4 perm, int act,
    long astride, long wstride, long cstride, int coffstride)
{
  __shared__ __align__(16) short As[128][40];   // stride 40 shorts = 80 B
  __shared__ __align__(16) short Bs[64][40];

  int z = blockIdx.z;
  A += (size_t)z * astride;
  W += (size_t)z * wstride;
  if (C)  C  += (size_t)z * cstride;
  if (Cb) Cb += (size_t)z * cstride;
  int permMode = (z == 0) ? perm.x : (z == 1) ? perm.y : (z == 2) ? perm.z : perm.w;
  int co = coff + z * coffstride;

  int tid = threadIdx.x;
  int m0 = blockIdx.x * 128;
  int n0 = blockIdx.y * 64;

  // staging coords
  int abr = tid >> 1;               // A row in tile 0..127
  int akq = (tid & 1) * 16;         // 0 or 16 (shorts)
  int arow = m0 + abr;
  int amrow = (arow & ~1023) | map_row(arow & 1023, permMode);
  const ushortx* ap = A + (size_t)amrow * lda + akq;
  int bn  = tid >> 2;               // B row (n) 0..63
  int bkq = (tid & 3) * 8;          // shorts
  const ushortx* wp = W + (size_t)(n0 + bn) * K + bkq;
  bool bok = (n0 + bn) < N;

  // compute coords
  int lane = tid & 63;
  int w = tid >> 6, wm = w >> 1, wn = w & 1;
  int lm = lane & 15, lq = lane >> 4;

  f32x4 acc[4][2];
  #pragma unroll
  for (int i = 0; i < 4; ++i)
    #pragma unroll
    for (int j = 0; j < 2; ++j) acc[i][j] = (f32x4){0.f, 0.f, 0.f, 0.f};

  for (int k0 = 0; k0 < K; k0 += 32) {
    // ---- stage A tile (128x32 bf16): pure 16B copies ----
    {
      bf16x8 t0 = *(const bf16x8*)(ap + k0);
      bf16x8 t1 = *(const bf16x8*)(ap + k0 + 8);
      *(bf16x8*)&As[abr][akq]     = t0;
      *(bf16x8*)&As[abr][akq + 8] = t1;
    }
    // ---- stage B tile (64x32 bf16) ----
    {
      bf16x8 t = {0,0,0,0,0,0,0,0};
      if (bok) t = *(const bf16x8*)(wp + k0);
      *(bf16x8*)&Bs[bn][bkq] = t;
    }
    __syncthreads();
    // ---- MFMA ----
    bf16x8 fa[4], fb[2];
    #pragma unroll
    for (int i = 0; i < 4; ++i)
      fa[i] = *(const bf16x8*)&As[wm * 64 + i * 16 + lm][lq * 8];
    #pragma unroll
    for (int j = 0; j < 2; ++j)
      fb[j] = *(const bf16x8*)&Bs[wn * 32 + j * 16 + lm][lq * 8];
    #pragma unroll
    for (int i = 0; i < 4; ++i)
      #pragma unroll
      for (int j = 0; j < 2; ++j)
        acc[i][j] = __builtin_amdgcn_mfma_f32_16x16x32_bf16(fa[i], fb[j], acc[i][j], 0, 0, 0);
    __syncthreads();
  }

  // ---- epilogue: C/D layout col=lane&15, row=quad*4+reg ----
  #pragma unroll
  for (int i = 0; i < 4; ++i) {
    #pragma unroll
    for (int r = 0; r < 4; ++r) {
      int row = m0 + wm * 64 + i * 16 + lq * 4 + r;
      #pragma unroll
      for (int j = 0; j < 2; ++j) {
        int n = n0 + wn * 32 + j * 16 + lm;
        if (n < N) {
          float v = acc[i][j][r];
          if (bias) v += bias[n];
          if (act == 1) v = 0.5f * v * (1.f + erff(v * 0.70710678118f)); // exact gelu
          if (C)  C [(size_t)row * ldc + co + n] = v;
          if (Cb) Cb[(size_t)row * ldc + co + n] = f2bf(v);
        }
      }
    }
  }
}

// ---------------- depthwise causal conv (k=4) + bias + silu -> fp32 + bf16 ----------------
__global__ __launch_bounds__(256) void conv_silu_kernel(
    const float* __restrict__ xz, const float* __restrict__ cw,
    const float* __restrict__ cb, float* __restrict__ xsm, ushortx* __restrict__ xsm_bf)
{
  int idx = blockIdx.x * 256 + threadIdx.x;   // 16*1024*384 total
  int d = idx % DI;
  int rest = idx / DI;
  int t = rest & 1023;
  int seq = rest >> 10;
  int k = seq >> 2;
  const float* xh = xz + (size_t)seq * L * (2 * DI) + d;
  const float* w = cw + ((size_t)k * DI + d) * 4;
  float acc = cb[k * DI + d];
  #pragma unroll
  for (int j = 0; j < 4; ++j) {
    int tt = t - 3 + j;
    if (tt >= 0) acc = fmaf(w[j], xh[(size_t)tt * (2 * DI)], acc);
  }
  float sig = 1.f / (1.f + __expf(-acc));
  float val = acc * sig;
  xsm[idx] = val;
  xsm_bf[idx] = f2bf(val);
}

// ---------------- dt = softplus(dbl[:, :12] @ Wdt^T + bdt) ----------------
__global__ __launch_bounds__(256) void dt_kernel(
    const float* __restrict__ dbl, const float* __restrict__ Wdt,
    const float* __restrict__ bdt, float* __restrict__ dt)
{
  int idx = blockIdx.x * 256 + threadIdx.x;   // 16*1024*384
  int d = idx % DI;
  int row = idx / DI;        // seq*1024 + t
  int k = row >> 12;
  const float* dl = dbl + (size_t)row * 44;
  const float* w = Wdt + ((size_t)k * DI + d) * DR;
  float acc = bdt[k * DI + d];
  #pragma unroll
  for (int r = 0; r < DR; ++r) acc = fmaf(w[r], dl[r], acc);
  dt[idx] = (acc > 20.f) ? acc : log1pf(__expf(acc));
}

// ---------------- scan pass 1: 1-wave blocks, register state, 4-deep prefetch ----------------
// grid (DI/64, 16 seqs, SEG); lane owns one channel, h[16] in registers.
__global__ __launch_bounds__(64) void scan_pass1(
    const float* __restrict__ dbl, const float* __restrict__ dt,
    const float* __restrict__ xsm, const float* __restrict__ Alog,
    float* __restrict__ hseg, float* __restrict__ Sseg)
{
  __shared__ __align__(16) float sB[ST][16];
  int seq = blockIdx.y, g = blockIdx.z, k = seq >> 2;
  int d = blockIdx.x * 64 + threadIdx.x;

  const float* bbase = dbl + ((size_t)seq * L + g * ST) * 44 + 12;
  #pragma unroll
  for (int j = 0; j < 8; ++j) {              // 512 float4 / 64 thr
    int i = threadIdx.x + j * 64;
    int t = i >> 2, q = (i & 3) * 4;
    *(float4*)&sB[t][q] = *(const float4*)(bbase + (size_t)t * 44 + q);
  }
  float A[16];
  const float* alp = Alog + ((size_t)k * DI + d) * DS;
  #pragma unroll
  for (int s = 0; s < 16; ++s) A[s] = -__expf(alp[s]);

  const float* dtp = dt  + ((size_t)seq * L + g * ST) * DI + d;
  const float* xp  = xsm + ((size_t)seq * L + g * ST) * DI + d;
  __syncthreads();

  float h[16];
  #pragma unroll
  for (int s = 0; s < 16; ++s) h[s] = 0.f;
  float sdt = 0.f;
  float rDt[4], rX[4];
  #pragma unroll
  for (int j = 0; j < 4; ++j) { rDt[j] = dtp[(size_t)j * DI]; rX[j] = xp[(size_t)j * DI]; }

  #pragma unroll 4
  for (int t = 0; t < ST - 4; ++t) {
    float dtv = rDt[t & 3], xv = rX[t & 3];
    rDt[t & 3] = dtp[(size_t)(t + 4) * DI];
    rX [t & 3] = xp [(size_t)(t + 4) * DI];
    float4 b0 = *(const float4*)&sB[t][0];
    float4 b1 = *(const float4*)&sB[t][4];
    float4 b2 = *(const float4*)&sB[t][8];
    float4 b3 = *(const float4*)&sB[t][12];
    float bv[16] = {b0.x,b0.y,b0.z,b0.w, b1.x,b1.y,b1.z,b1.w,
                    b2.x,b2.y,b2.z,b2.w, b3.x,b3.y,b3.z,b3.w};
    float dtx = dtv * xv;
    sdt += dtv;
    #pragma unroll
    for (int s = 0; s < 16; ++s) {
      float dA = __expf(dtv * A[s]);
      h[s] = fmaf(dA, h[s], dtx * bv[s]);
    }
  }
  #pragma unroll
  for (int t = ST - 4; t < ST; ++t) {
    float dtv = rDt[t & 3], xv = rX[t & 3];
    float4 b0 = *(const float4*)&sB[t][0];
    float4 b1 = *(const float4*)&sB[t][4];
    float4 b2 = *(const float4*)&sB[t][8];
    float4 b3 = *(const float4*)&sB[t][12];
    float bv[16] = {b0.x,b0.y,b0.z,b0.w, b1.x,b1.y,b1.z,b1.w,
                    b2.x,b2.y,b2.z,b2.w, b3.x,b3.y,b3.z,b3.w};
    float dtx = dtv * xv;
    sdt += dtv;
    #pragma unroll
    for (int s = 0; s < 16; ++s) {
      float dA = __expf(dtv * A[s]);
      h[s] = fmaf(dA, h[s], dtx * bv[s]);
    }
  }
  float* hp = hseg + (((size_t)seq * SEG + g) * DI + d) * DS;
  #pragma unroll
  for (int s = 0; s < 16; ++s) hp[s] = h[s];
  Sseg[((size_t)seq * SEG + g) * DI + d] = sdt;
}

// ---------------- scan pass 2: 1-wave blocks, init correction + scan + gate -> y bf16 ----------------
// grid (DI/64, 16 seqs, SEG)
__global__ __launch_bounds__(64) void scan_pass2(
    const float* __restrict__ dbl, const float* __restrict__ dt,
    const float* __restrict__ xz, const float* __restrict__ xsm,
    ushortx* __restrict__ ybf,
    const float* __restrict__ Alog, const float* __restrict__ Dp,
    const float* __restrict__ hseg, const float* __restrict__ Sseg)
{
  __shared__ __align__(16) float sBC[ST][32];
  int seq = blockIdx.y, g = blockIdx.z, k = seq >> 2;
  int d = blockIdx.x * 64 + threadIdx.x;

  const float* bcbase = dbl + ((size_t)seq * L + g * ST) * 44 + 12;
  #pragma unroll
  for (int j = 0; j < 16; ++j) {             // 1024 float4 / 64 thr
    int i = threadIdx.x + j * 64;
    int t = i >> 3, q = (i & 7) * 4;
    *(float4*)&sBC[t][q] = *(const float4*)(bcbase + (size_t)t * 44 + q);
  }
  float A[16];
  const float* alp = Alog + ((size_t)k * DI + d) * DS;
  #pragma unroll
  for (int s = 0; s < 16; ++s) A[s] = -__expf(alp[s]);
  float Dv = Dp[k * DI + d];

  // closed-form initial state: h = sum_j hseg_j * exp(A * sum_{j<u<g} S_u)
  float h[16];
  #pragma unroll
  for (int s = 0; s < 16; ++s) h[s] = 0.f;
  {
    float cumS = 0.f;
    for (int j = g - 1; j >= 0; --j) {
      const float* hp = hseg + (((size_t)seq * SEG + j) * DI + d) * DS;
      float Sj = Sseg[((size_t)seq * SEG + j) * DI + d];
      #pragma unroll
      for (int s = 0; s < 16; ++s)
        h[s] = fmaf(hp[s], __expf(A[s] * cumS), h[s]);
      cumS += Sj;
    }
  }

  const float* dtp = dt  + ((size_t)seq * L + g * ST) * DI + d;
  const float* zp  = xz  + ((size_t)seq * L + g * ST) * (2 * DI) + DI + d;
  const float* xpp = xsm + ((size_t)seq * L + g * ST) * DI + d;
  ushortx*     yp  = ybf + ((size_t)seq * L + g * ST) * DI + d;
  __syncthreads();

  float rDt[4], rX[4], rZ[4];
  #pragma unroll
  for (int j = 0; j < 4; ++j) {
    rDt[j] = dtp[(size_t)j * DI];
    rX [j] = xpp[(size_t)j * DI];
    rZ [j] = zp [(size_t)j * (2 * DI)];
  }

  #pragma unroll 4
  for (int t = 0; t < ST - 4; ++t) {
    float dtv = rDt[t & 3], xv = rX[t & 3], zv = rZ[t & 3];
    rDt[t & 3] = dtp[(size_t)(t + 4) * DI];
    rX [t & 3] = xpp[(size_t)(t + 4) * DI];
    rZ [t & 3] = zp [(size_t)(t + 4) * (2 * DI)];
    float4 b0 = *(const float4*)&sBC[t][0];
    float4 b1 = *(const float4*)&sBC[t][4];
    float4 b2 = *(const float4*)&sBC[t][8];
    float4 b3 = *(const float4*)&sBC[t][12];
    float4 c0 = *(const float4*)&sBC[t][16];
    float4 c1 = *(const float4*)&sBC[t][20];
    float4 c2 = *(const float4*)&sBC[t][24];
    float4 c3 = *(const float4*)&sBC[t][28];
    float bv[16] = {b0.x,b0.y,b0.z,b0.w, b1.x,b1.y,b1.z,b1.w,
                    b2.x,b2.y,b2.z,b2.w, b3.x,b3.y,b3.z,b3.w};
    float cv[16] = {c0.x,c0.y,c0.z,c0.w, c1.x,c1.y,c1.z,c1.w,
                    c2.x,c2.y,c2.z,c2.w, c3.x,c3.y,c3.z,c3.w};
    float dtx = dtv * xv;
    float y = 0.f;
    #pragma unroll
    for (int s = 0; s < 16; ++s) {
      float dA = __expf(dtv * A[s]);
      h[s] = fmaf(dA, h[s], dtx * bv[s]);
      y = fmaf(h[s], cv[s], y);
    }
    y = fmaf(Dv, xv, y);
    float sig = 1.f / (1.f + __expf(-zv));
    yp[(size_t)t * DI] = f2bf(y * (zv * sig));
  }
  #pragma unroll
  for (int t = ST - 4; t < ST; ++t) {
    float dtv = rDt[t & 3], xv = rX[t & 3], zv = rZ[t & 3];
    float4 b0 = *(const float4*)&sBC[t][0];
    float4 b1 = *(const float4*)&sBC[t][4];
    float4 b2 = *(const float4*)&sBC[t][8];
    float4 b3 = *(const float4*)&sBC[t][12];
    float4 c0 = *(const float4*)&sBC[t][16];
    float4 c1 = *(const float4*)&sBC[t][20];
    float4 c2 = *(const float4*)&sBC[t][24];
    float4 c3 = *(const float4*)&sBC[t][28];
    float bv[16] = {b0.x,b0.y,b0.z,b0.w, b1.x,b1.y,b1.z,b1.w,
                    b2.x,b2.y,b2.z,b2.w, b3.x,b3.y,b3.z,b3.w};
    float cv[16] = {c0.x,c0.y,c0.z,c0.w, c1.x,c1.y,c1.z,c1.w,
                    c2.x,c2.y,c2.z,c2.w, c3.x,c3.y,c3.z,c3.w};
    float dtx = dtv * xv;
    float y = 0.f;
    #pragma unroll
    for (int s = 0; s < 16; ++s) {
      float dA = __expf(dtv * A[s]);
      h[s] = fmaf(dA, h[s], dtx * bv[s]);
      y = fmaf(h[s], cv[s], y);
    }
    y = fmaf(Dv, xv, y);
    float sig = 1.f / (1.f + __expf(-zv));
    yp[(size_t)t * DI] = f2bf(y * (zv * sig));
  }
}

// ---------------- final LN + residual, write (B,192,H,W) ----------------
__global__ __launch_bounds__(256) void ln_out_kernel(
    const float* __restrict__ outp, const float* __restrict__ g,
    const float* __restrict__ b, const float* __restrict__ xs,
    float* __restrict__ out)
{
  int wave = threadIdx.x >> 6;
  int lane = threadIdx.x & 63;
  int r = blockIdx.x * 4 + wave;
  int bb = r >> 10, n = r & 1023;
  const float* xr = outp + (size_t)r * DM;
  float v[3];
  float s = 0.f, s2 = 0.f;
  #pragma unroll
  for (int j = 0; j < 3; ++j) {
    int c = lane + j * 64;
    v[j] = xr[c];
    s += v[j]; s2 += v[j] * v[j];
  }
  s = wave_sum(s); s2 = wave_sum(s2);
  float mean = s * (1.f / DM);
  float var  = s2 * (1.f / DM) - mean * mean;
  float rstd = rsqrtf(var + 1e-5f);
  const float* xsr = xs + (size_t)r * DM;
  #pragma unroll
  for (int j = 0; j < 3; ++j) {
    int c = lane + j * 64;
    out[(size_t)bb * DM * L + (size_t)c * L + n] =
        (v[j] - mean) * rstd * g[c] + b[c] + xsr[c];
  }
}

// ---------------- host side ----------------
static inline void gemm(const ushortx* A, int lda, const ushortx* W, const float* bias,
                        float* C, ushortx* Cb,
                        int N, int K, int ldc, int coff, int4 perm, int act,
                        int nz, long astride, long wstride, long cstride, int coffstride,
                        hipStream_t s) {
  dim3 grid(ROWS / 128, (N + 63) / 64, nz);
  gemm_kernel<<<grid, 256, 0, s>>>(A, lda, W, bias, C, Cb, N, K, ldc, coff, perm, act,
                                   astride, wstride, cstride, coffstride);
}

extern "C" void kernel_launch(void* const* d_in, const int* in_sizes, int n_in,
                              void* d_out, int out_size, void* d_ws, size_t ws_size,
                              hipStream_t stream) {
  (void)in_sizes; (void)n_in; (void)out_size; (void)ws_size;
  const float* x        = (const float*)d_in[0];
  const float* norm_g   = (const float*)d_in[1];
  const float* norm_b   = (const float*)d_in[2];
  const float* in_w     = (const float*)d_in[3];
  const float* in_b     = (const float*)d_in[4];
  const float* m_in_w   = (const float*)d_in[5];
  const float* m_conv_w = (const float*)d_in[6];
  const float* m_conv_b = (const float*)d_in[7];
  const float* m_xp_w   = (const float*)d_in[8];
  const float* m_dt_w   = (const float*)d_in[9];
  const float* m_dt_b   = (const float*)d_in[10];
  const float* m_Alog   = (const float*)d_in[11];
  const float* m_D      = (const float*)d_in[12];
  const float* m_out_w  = (const float*)d_in[13];
  const float* f_w1     = (const float*)d_in[14];
  const float* f_b1     = (const float*)d_in[15];
  const float* f_w2     = (const float*)d_in[16];
  const float* f_b2     = (const float*)d_in[17];
  const float* o_w      = (const float*)d_in[18];
  const float* o_b      = (const float*)d_in[19];
  const float* on_g     = (const float*)d_in[20];
  const float* on_b     = (const float*)d_in[21];
  float* out = (float*)d_out;

  // ---- workspace layout (float-slot units) ----
  float* ws   = (float*)d_ws;
  float* xs   = ws;                        // 786432
  float* hseg = xs + 786432;               // 786432
  float* xz   = hseg + 786432;             // 12582912
  float* xsm  = xz + 12582912;             // 6291456
  float* dbl  = xsm + 6291456;             // 720896
  float* dtb  = dbl + 720896;              // 6291456
  float* Sseg = dtb + 6291456;             // 49152
  ushortx* xs_bf  = (ushortx*)(Sseg + 49152);   // 786432 sh
  ushortx* xp_bf  = xs_bf + 786432;             // 786432 sh
  ushortx* wbf    = xp_bf + 786432;             // 1394688 sh
  ushortx* shared_bf = wbf + 1394688;           // 6291456 sh (xsm_bf, later ybf)
  // xz region is dead after scan -> alias post-scan bf16/fp32 buffers into it
  ushortx* fused_bf = (ushortx*)xz;             // 3145728 sh
  ushortx* hdn_bf   = fused_bf + 3145728;       // 1572864 sh
  ushortx* h2_bf    = hdn_bf + 1572864;         // 786432 sh
  float*   outp     = xz + 2752512;             // 786432 f32 (after the 3 bf16 bufs)

  // weight offsets in wbf (shorts)
  const unsigned W_IN = 0, W_MIN = 36864, W_XP = 626688, W_OUT = 694272,
                 W_F1 = 989184, W_F2 = 1284096, W_O = 1357824;

  int4 p0 = make_int4(0, 0, 0, 0);
  int4 pfwd = make_int4(0, 1, 2, 3);
  int4 pinv = make_int4(0, 1, 2, 4);

  // 0) weights -> bf16 (once per call)
  {
    WcvtArgs a;
    a.src[0] = in_w;    a.off[0] = W_IN;  a.n[0] = 36864;
    a.src[1] = m_in_w;  a.off[1] = W_MIN; a.n[1] = 589824;
    a.src[2] = m_xp_w;  a.off[2] = W_XP;  a.n[2] = 67584;
    a.src[3] = m_out_w; a.off[3] = W_OUT; a.n[3] = 294912;
    a.src[4] = f_w1;    a.off[4] = W_F1;  a.n[4] = 294912;
    a.src[5] = f_w2;    a.off[5] = W_F2;  a.n[5] = 73728;
    a.src[6] = o_w;     a.off[6] = W_O;   a.n[6] = 36864;
    wcvt_kernel<<<dim3(576, 7), 256, 0, stream>>>(a, wbf);
  }
  // 1) input layernorm + transpose -> xs fp32 + bf16
  ln_in_kernel<<<1024, 256, 0, stream>>>(x, norm_g, norm_b, xs, xs_bf);
  // 2) xp = xs @ in_w^T + in_b  (bf16 out only)
  gemm(xs_bf, DM, wbf + W_IN, in_b, nullptr, xp_bf, DM, DM, DM, 0, p0, 0,
       1, 0, 0, 0, 0, stream);
  // 3) xz_k = perm_k(xp) @ Win_k^T (fp32 out), one dispatch, z = direction
  gemm(xp_bf, DM, wbf + W_MIN, nullptr, xz, nullptr, 2 * DI, DM, 2 * DI, 0, pfwd, 0,
       4, 0, (long)2 * DI * DM, (long)ROWS * 2 * DI, 0, stream);
  // 4) depthwise causal conv + silu -> xsm fp32 + bf16
  conv_silu_kernel<<<(16 * L * DI) / 256, 256, 0, stream>>>(xz, m_conv_w, m_conv_b, xsm, shared_bf);
  // 5) dbl_k = xsm_k @ Wxp_k^T (N=44, fp32 out), one dispatch
  gemm(shared_bf, DI, wbf + W_XP, nullptr, dbl, nullptr, 44, DI, 44, 0, p0, 0,
       4, (long)ROWS * DI, (long)44 * DI, (long)ROWS * 44, 0, stream);
  // 6) dt = softplus(dbl[:,:12] @ Wdt^T + bdt)
  dt_kernel<<<(16 * L * DI) / 256, 256, 0, stream>>>(dbl, m_dt_w, m_dt_b, dtb);
  // 7) two-pass time-segmented selective scan (+ D skip + silu(z) gate) -> ybf (bf16)
  scan_pass1<<<dim3(DI / 64, 16, SEG), 64, 0, stream>>>(dbl, dtb, xsm, m_Alog, hseg, Sseg);
  scan_pass2<<<dim3(DI / 64, 16, SEG), 64, 0, stream>>>(dbl, dtb, xz, xsm, shared_bf,
                                                        m_Alog, m_D, hseg, Sseg);
  // 8) out-proj per direction (gather inverse perm), scatter into fused cols (bf16 out)
  gemm(shared_bf, DI, wbf + W_OUT, nullptr, nullptr, fused_bf, DM, DI, 4 * DM, 0, pinv, 0,
       4, (long)ROWS * DI, (long)DM * DI, 0, DM, stream);
  // 9) MLP
  gemm(fused_bf, 4 * DM, wbf + W_F1, f_b1, nullptr, hdn_bf, 2 * DM, 4 * DM, 2 * DM, 0, p0, 1,
       1, 0, 0, 0, 0, stream); // gelu
  gemm(hdn_bf, 2 * DM, wbf + W_F2, f_b2, nullptr, h2_bf, DM, 2 * DM, DM, 0, p0, 0,
       1, 0, 0, 0, 0, stream);
  // 10) out proj (fp32 out)
  gemm(h2_bf, DM, wbf + W_O, o_b, outp, nullptr, DM, DM, DM, 0, p0, 0,
       1, 0, 0, 0, 0, stream);
  // 11) final LN + residual + transpose to (B,192,H,W)
  ln_out_kernel<<<1024, 256, 0, stream>>>(outp, on_g, on_b, xs, out);
}

// Round 7
// 348.953 us; speedup vs baseline: 4.6261x; 1.0767x over previous
//
#include <hip/hip_runtime.h>
#include <cstddef>

#define DM 192
#define DI 384
#define DS 16
#define DR 12
#define L 1024
#define ROWS 4096   // B*N = 4*1024
#define SEG 32      // time segments for two-pass scan
#define ST  32      // steps per segment

typedef unsigned short ushortx;
typedef short bf16x8 __attribute__((ext_vector_type(8)));
typedef float f32x4  __attribute__((ext_vector_type(4)));

// ---------------- helpers ----------------
__device__ __forceinline__ float wave_sum(float v) {
  #pragma unroll
  for (int off = 32; off > 0; off >>= 1) v += __shfl_xor(v, off);
  return v;
}

__device__ __forceinline__ ushortx f2bf(float x) {   // fp32 -> bf16 RNE
  unsigned u = __float_as_uint(x);
  u += 0x7fffu + ((u >> 16) & 1u);
  return (ushortx)(u >> 16);
}

// row permutation within each batch's 1024 rows
__device__ __forceinline__ int map_row(int t, int mode) {
  switch (mode) {
    case 1: return 1023 - t;                                   // flip
    case 2: return ((t & 31) << 5) | (t >> 5);                 // 32x32 transpose
    case 3: { int u = 1023 - t; return ((u & 31) << 5) | (u >> 5); } // perm(flip)
    case 4: return 1023 - (((t & 31) << 5) | (t >> 5));        // flip(perm)
    default: return t;
  }
}

// ---------------- weight fp32 -> bf16 pre-conversion (7 tensors, one kernel) ----------------
struct WcvtArgs {
  const float* src[7];
  unsigned int off[7];   // dst offset in shorts
  unsigned int n[7];     // element count
};
__global__ __launch_bounds__(256) void wcvt_kernel(WcvtArgs a, ushortx* __restrict__ dst) {
  int w = blockIdx.y;
  int i = (blockIdx.x * 256 + threadIdx.x) * 4;
  if (i >= (int)a.n[w]) return;
  float4 v = *(const float4*)(a.src[w] + i);
  ushort4 o;
  o.x = f2bf(v.x); o.y = f2bf(v.y); o.z = f2bf(v.z); o.w = f2bf(v.w);
  *(ushort4*)(dst + a.off[w] + i) = o;
}

// ---------------- LN on input (B,192,H,W) -> xs fp32 + bf16 ----------------
__global__ __launch_bounds__(256) void ln_in_kernel(
    const float* __restrict__ x, const float* __restrict__ g,
    const float* __restrict__ b, float* __restrict__ xs, ushortx* __restrict__ xs_bf)
{
  int wave = threadIdx.x >> 6;
  int lane = threadIdx.x & 63;
  int r = blockIdx.x * 4 + wave;          // b*1024 + n
  int bb = r >> 10, n = r & 1023;
  const float* xb = x + (size_t)bb * DM * L + n;
  float v[3];
  float s = 0.f, s2 = 0.f;
  #pragma unroll
  for (int j = 0; j < 3; ++j) {
    int c = lane + j * 64;
    v[j] = xb[(size_t)c * L];
    s += v[j]; s2 += v[j] * v[j];
  }
  s = wave_sum(s); s2 = wave_sum(s2);
  float mean = s * (1.f / DM);
  float var  = s2 * (1.f / DM) - mean * mean;
  float rstd = rsqrtf(var + 1e-5f);
  float* xo = xs + (size_t)r * DM;
  ushortx* xob = xs_bf + (size_t)r * DM;
  #pragma unroll
  for (int j = 0; j < 3; ++j) {
    int c = lane + j * 64;
    float val = (v[j] - mean) * rstd * g[c] + b[c];
    xo[c] = val;
    xob[c] = f2bf(val);
  }
}

// ---------------- bf16 MFMA GEMM, all-bf16 operands, gridDim.z batching ----------------
// out = act(permA_z(m) @ W_z^T + bias); C (fp32) and/or Cb (bf16) outputs.
// BM=128, BN templated (64 or 128), BK=32; 256 threads = 4 waves (2x2).
// wave tile 64 x (BN/2).
template <int BN>
__global__ __launch_bounds__(256) void gemm_kernel(
    const ushortx* __restrict__ A, int lda, const ushortx* __restrict__ W,
    const float* __restrict__ bias, float* __restrict__ C, ushortx* __restrict__ Cb,
    int N, int K, int ldc, int coff, int4 perm, int act,
    long astride, long wstride, long cstride, int coffstride)
{
  constexpr int NF = BN / 32;                    // n-frags per wave
  __shared__ __align__(16) short As[128][40];    // stride 40 shorts = 80 B
  __shared__ __align__(16) short Bs[BN][40];

  int z = blockIdx.z;
  A += (size_t)z * astride;
  W += (size_t)z * wstride;
  if (C)  C  += (size_t)z * cstride;
  if (Cb) Cb += (size_t)z * cstride;
  int permMode = (z == 0) ? perm.x : (z == 1) ? perm.y : (z == 2) ? perm.z : perm.w;
  int co = coff + z * coffstride;

  int tid = threadIdx.x;
  int m0 = blockIdx.x * 128;
  int n0 = blockIdx.y * BN;

  // staging coords
  int abr = tid >> 1;               // A row in tile 0..127
  int akq = (tid & 1) * 16;         // 0 or 16 (shorts)
  int arow = m0 + abr;
  int amrow = (arow & ~1023) | map_row(arow & 1023, permMode);
  const ushortx* ap = A + (size_t)amrow * lda + akq;

  int bn, bkq;
  if (BN == 64) { bn = tid >> 2; bkq = (tid & 3) * 8; }
  else          { bn = tid >> 1; bkq = (tid & 1) * 16; }
  const ushortx* wp = W + (size_t)(n0 + bn) * K + bkq;
  bool bok = (n0 + bn) < N;

  // compute coords
  int lane = tid & 63;
  int w = tid >> 6, wm = w >> 1, wn = w & 1;
  int lm = lane & 15, lq = lane >> 4;

  f32x4 acc[4][NF];
  #pragma unroll
  for (int i = 0; i < 4; ++i)
    #pragma unroll
    for (int j = 0; j < NF; ++j) acc[i][j] = (f32x4){0.f, 0.f, 0.f, 0.f};

  for (int k0 = 0; k0 < K; k0 += 32) {
    // ---- stage A tile (128x32 bf16): pure 16B copies ----
    {
      bf16x8 t0 = *(const bf16x8*)(ap + k0);
      bf16x8 t1 = *(const bf16x8*)(ap + k0 + 8);
      *(bf16x8*)&As[abr][akq]     = t0;
      *(bf16x8*)&As[abr][akq + 8] = t1;
    }
    // ---- stage B tile (BNx32 bf16) ----
    if (BN == 64) {
      bf16x8 t = {0,0,0,0,0,0,0,0};
      if (bok) t = *(const bf16x8*)(wp + k0);
      *(bf16x8*)&Bs[bn][bkq] = t;
    } else {
      bf16x8 t0 = {0,0,0,0,0,0,0,0}, t1 = t0;
      if (bok) { t0 = *(const bf16x8*)(wp + k0); t1 = *(const bf16x8*)(wp + k0 + 8); }
      *(bf16x8*)&Bs[bn][bkq]     = t0;
      *(bf16x8*)&Bs[bn][bkq + 8] = t1;
    }
    __syncthreads();
    // ---- MFMA ----
    bf16x8 fa[4], fb[NF];
    #pragma unroll
    for (int i = 0; i < 4; ++i)
      fa[i] = *(const bf16x8*)&As[wm * 64 + i * 16 + lm][lq * 8];
    #pragma unroll
    for (int j = 0; j < NF; ++j)
      fb[j] = *(const bf16x8*)&Bs[wn * (BN / 2) + j * 16 + lm][lq * 8];
    #pragma unroll
    for (int i = 0; i < 4; ++i)
      #pragma unroll
      for (int j = 0; j < NF; ++j)
        acc[i][j] = __builtin_amdgcn_mfma_f32_16x16x32_bf16(fa[i], fb[j], acc[i][j], 0, 0, 0);
    __syncthreads();
  }

  // ---- epilogue: C/D layout col=lane&15, row=quad*4+reg ----
  #pragma unroll
  for (int i = 0; i < 4; ++i) {
    #pragma unroll
    for (int r = 0; r < 4; ++r) {
      int row = m0 + wm * 64 + i * 16 + lq * 4 + r;
      #pragma unroll
      for (int j = 0; j < NF; ++j) {
        int n = n0 + wn * (BN / 2) + j * 16 + lm;
        if (n < N) {
          float v = acc[i][j][r];
          if (bias) v += bias[n];
          if (act == 1) v = 0.5f * v * (1.f + erff(v * 0.70710678118f)); // exact gelu
          if (C)  C [(size_t)row * ldc + co + n] = v;
          if (Cb) Cb[(size_t)row * ldc + co + n] = f2bf(v);
        }
      }
    }
  }
}

// ---------------- depthwise causal conv (k=4) + bias + silu -> fp32 + bf16 ----------------
__global__ __launch_bounds__(256) void conv_silu_kernel(
    const float* __restrict__ xz, const float* __restrict__ cw,
    const float* __restrict__ cb, float* __restrict__ xsm, ushortx* __restrict__ xsm_bf)
{
  int idx = blockIdx.x * 256 + threadIdx.x;   // 16*1024*384 total
  int d = idx % DI;
  int rest = idx / DI;
  int t = rest & 1023;
  int seq = rest >> 10;
  int k = seq >> 2;
  const float* xh = xz + (size_t)seq * L * (2 * DI) + d;
  const float* w = cw + ((size_t)k * DI + d) * 4;
  float acc = cb[k * DI + d];
  #pragma unroll
  for (int j = 0; j < 4; ++j) {
    int tt = t - 3 + j;
    if (tt >= 0) acc = fmaf(w[j], xh[(size_t)tt * (2 * DI)], acc);
  }
  float sig = 1.f / (1.f + __expf(-acc));
  float val = acc * sig;
  xsm[idx] = val;
  xsm_bf[idx] = f2bf(val);
}

// ---------------- dt = softplus(dbl[:, :12] @ Wdt^T + bdt) ----------------
__global__ __launch_bounds__(256) void dt_kernel(
    const float* __restrict__ dbl, const float* __restrict__ Wdt,
    const float* __restrict__ bdt, float* __restrict__ dt)
{
  int idx = blockIdx.x * 256 + threadIdx.x;   // 16*1024*384
  int d = idx % DI;
  int row = idx / DI;        // seq*1024 + t
  int k = row >> 12;
  const float* dl = dbl + (size_t)row * 44;
  const float* w = Wdt + ((size_t)k * DI + d) * DR;
  float acc = bdt[k * DI + d];
  #pragma unroll
  for (int r = 0; r < DR; ++r) acc = fmaf(w[r], dl[r], acc);
  dt[idx] = (acc > 20.f) ? acc : log1pf(__expf(acc));
}

// ---------------- scan pass 1: 1-wave blocks, register state, 4-deep prefetch ----------------
// grid (DI/64, 16 seqs, SEG); lane owns one channel, h[16] in registers.
__global__ __launch_bounds__(64) void scan_pass1(
    const float* __restrict__ dbl, const float* __restrict__ dt,
    const float* __restrict__ xsm, const float* __restrict__ Alog,
    float* __restrict__ hseg, float* __restrict__ Sseg)
{
  __shared__ __align__(16) float sB[ST][16];
  int seq = blockIdx.y, g = blockIdx.z, k = seq >> 2;
  int d = blockIdx.x * 64 + threadIdx.x;

  const float* bbase = dbl + ((size_t)seq * L + g * ST) * 44 + 12;
  #pragma unroll
  for (int j = 0; j < (ST * 16) / (4 * 64); ++j) {   // float4s / 64 thr
    int i = threadIdx.x + j * 64;
    int t = i >> 2, q = (i & 3) * 4;
    *(float4*)&sB[t][q] = *(const float4*)(bbase + (size_t)t * 44 + q);
  }
  float A[16];
  const float* alp = Alog + ((size_t)k * DI + d) * DS;
  #pragma unroll
  for (int s = 0; s < 16; ++s) A[s] = -__expf(alp[s]);

  const float* dtp = dt  + ((size_t)seq * L + g * ST) * DI + d;
  const float* xp  = xsm + ((size_t)seq * L + g * ST) * DI + d;
  __syncthreads();

  float h[16];
  #pragma unroll
  for (int s = 0; s < 16; ++s) h[s] = 0.f;
  float sdt = 0.f;
  float rDt[4], rX[4];
  #pragma unroll
  for (int j = 0; j < 4; ++j) { rDt[j] = dtp[(size_t)j * DI]; rX[j] = xp[(size_t)j * DI]; }

  #pragma unroll 4
  for (int t = 0; t < ST - 4; ++t) {
    float dtv = rDt[t & 3], xv = rX[t & 3];
    rDt[t & 3] = dtp[(size_t)(t + 4) * DI];
    rX [t & 3] = xp [(size_t)(t + 4) * DI];
    float4 b0 = *(const float4*)&sB[t][0];
    float4 b1 = *(const float4*)&sB[t][4];
    float4 b2 = *(const float4*)&sB[t][8];
    float4 b3 = *(const float4*)&sB[t][12];
    float bv[16] = {b0.x,b0.y,b0.z,b0.w, b1.x,b1.y,b1.z,b1.w,
                    b2.x,b2.y,b2.z,b2.w, b3.x,b3.y,b3.z,b3.w};
    float dtx = dtv * xv;
    sdt += dtv;
    #pragma unroll
    for (int s = 0; s < 16; ++s) {
      float dA = __expf(dtv * A[s]);
      h[s] = fmaf(dA, h[s], dtx * bv[s]);
    }
  }
  #pragma unroll
  for (int t = ST - 4; t < ST; ++t) {
    float dtv = rDt[t & 3], xv = rX[t & 3];
    float4 b0 = *(const float4*)&sB[t][0];
    float4 b1 = *(const float4*)&sB[t][4];
    float4 b2 = *(const float4*)&sB[t][8];
    float4 b3 = *(const float4*)&sB[t][12];
    float bv[16] = {b0.x,b0.y,b0.z,b0.w, b1.x,b1.y,b1.z,b1.w,
                    b2.x,b2.y,b2.z,b2.w, b3.x,b3.y,b3.z,b3.w};
    float dtx = dtv * xv;
    sdt += dtv;
    #pragma unroll
    for (int s = 0; s < 16; ++s) {
      float dA = __expf(dtv * A[s]);
      h[s] = fmaf(dA, h[s], dtx * bv[s]);
    }
  }
  float* hp = hseg + (((size_t)seq * SEG + g) * DI + d) * DS;
  #pragma unroll
  for (int s = 0; s < 16; ++s) hp[s] = h[s];
  Sseg[((size_t)seq * SEG + g) * DI + d] = sdt;
}

// ---------------- scan mid: fold segment states serially; hseg[g] <- H_init(g) in place ----
// grid (DI/64, 16); lane owns one channel.
__global__ __launch_bounds__(64) void scan_mid(
    float* __restrict__ hseg, const float* __restrict__ Sseg,
    const float* __restrict__ Alog)
{
  int seq = blockIdx.y, k = seq >> 2;
  int d = blockIdx.x * 64 + threadIdx.x;
  float A[16];
  const float* alp = Alog + ((size_t)k * DI + d) * DS;
  #pragma unroll
  for (int s = 0; s < 16; ++s) A[s] = -__expf(alp[s]);
  float h[16];
  #pragma unroll
  for (int s = 0; s < 16; ++s) h[s] = 0.f;
  for (int g = 0; g < SEG; ++g) {
    float* hp = hseg + (((size_t)seq * SEG + g) * DI + d) * DS;
    float Sg = Sseg[((size_t)seq * SEG + g) * DI + d];
    float tmp[16];
    #pragma unroll
    for (int s = 0; s < 16; ++s) tmp[s] = hp[s];
    #pragma unroll
    for (int s = 0; s < 16; ++s) hp[s] = h[s];           // corrected init for seg g
    #pragma unroll
    for (int s = 0; s < 16; ++s)
      h[s] = fmaf(h[s], __expf(A[s] * Sg), tmp[s]);      // advance past seg g
  }
}

// ---------------- scan pass 2: 1-wave blocks, init from hseg + scan + gate -> y bf16 ------
// grid (DI/64, 16 seqs, SEG)
__global__ __launch_bounds__(64) void scan_pass2(
    const float* __restrict__ dbl, const float* __restrict__ dt,
    const float* __restrict__ xz, const float* __restrict__ xsm,
    ushortx* __restrict__ ybf,
    const float* __restrict__ Alog, const float* __restrict__ Dp,
    const float* __restrict__ hseg)
{
  __shared__ __align__(16) float sBC[ST][32];
  int seq = blockIdx.y, g = blockIdx.z, k = seq >> 2;
  int d = blockIdx.x * 64 + threadIdx.x;

  const float* bcbase = dbl + ((size_t)seq * L + g * ST) * 44 + 12;
  #pragma unroll
  for (int j = 0; j < (ST * 32) / (4 * 64); ++j) {   // float4s / 64 thr
    int i = threadIdx.x + j * 64;
    int t = i >> 3, q = (i & 7) * 4;
    *(float4*)&sBC[t][q] = *(const float4*)(bcbase + (size_t)t * 44 + q);
  }
  float A[16];
  const float* alp = Alog + ((size_t)k * DI + d) * DS;
  #pragma unroll
  for (int s = 0; s < 16; ++s) A[s] = -__expf(alp[s]);
  float Dv = Dp[k * DI + d];

  // corrected initial state (written by scan_mid)
  float h[16];
  {
    const float* hp = hseg + (((size_t)seq * SEG + g) * DI + d) * DS;
    #pragma unroll
    for (int s = 0; s < 16; ++s) h[s] = hp[s];
  }

  const float* dtp = dt  + ((size_t)seq * L + g * ST) * DI + d;
  const float* zp  = xz  + ((size_t)seq * L + g * ST) * (2 * DI) + DI + d;
  const float* xpp = xsm + ((size_t)seq * L + g * ST) * DI + d;
  ushortx*     yp  = ybf + ((size_t)seq * L + g * ST) * DI + d;
  __syncthreads();

  float rDt[4], rX[4], rZ[4];
  #pragma unroll
  for (int j = 0; j < 4; ++j) {
    rDt[j] = dtp[(size_t)j * DI];
    rX [j] = xpp[(size_t)j * DI];
    rZ [j] = zp [(size_t)j * (2 * DI)];
  }

  #pragma unroll 4
  for (int t = 0; t < ST - 4; ++t) {
    float dtv = rDt[t & 3], xv = rX[t & 3], zv = rZ[t & 3];
    rDt[t & 3] = dtp[(size_t)(t + 4) * DI];
    rX [t & 3] = xpp[(size_t)(t + 4) * DI];
    rZ [t & 3] = zp [(size_t)(t + 4) * (2 * DI)];
    float4 b0 = *(const float4*)&sBC[t][0];
    float4 b1 = *(const float4*)&sBC[t][4];
    float4 b2 = *(const float4*)&sBC[t][8];
    float4 b3 = *(const float4*)&sBC[t][12];
    float4 c0 = *(const float4*)&sBC[t][16];
    float4 c1 = *(const float4*)&sBC[t][20];
    float4 c2 = *(const float4*)&sBC[t][24];
    float4 c3 = *(const float4*)&sBC[t][28];
    float bv[16] = {b0.x,b0.y,b0.z,b0.w, b1.x,b1.y,b1.z,b1.w,
                    b2.x,b2.y,b2.z,b2.w, b3.x,b3.y,b3.z,b3.w};
    float cv[16] = {c0.x,c0.y,c0.z,c0.w, c1.x,c1.y,c1.z,c1.w,
                    c2.x,c2.y,c2.z,c2.w, c3.x,c3.y,c3.z,c3.w};
    float dtx = dtv * xv;
    float y = 0.f;
    #pragma unroll
    for (int s = 0; s < 16; ++s) {
      float dA = __expf(dtv * A[s]);
      h[s] = fmaf(dA, h[s], dtx * bv[s]);
      y = fmaf(h[s], cv[s], y);
    }
    y = fmaf(Dv, xv, y);
    float sig = 1.f / (1.f + __expf(-zv));
    yp[(size_t)t * DI] = f2bf(y * (zv * sig));
  }
  #pragma unroll
  for (int t = ST - 4; t < ST; ++t) {
    float dtv = rDt[t & 3], xv = rX[t & 3], zv = rZ[t & 3];
    float4 b0 = *(const float4*)&sBC[t][0];
    float4 b1 = *(const float4*)&sBC[t][4];
    float4 b2 = *(const float4*)&sBC[t][8];
    float4 b3 = *(const float4*)&sBC[t][12];
    float4 c0 = *(const float4*)&sBC[t][16];
    float4 c1 = *(const float4*)&sBC[t][20];
    float4 c2 = *(const float4*)&sBC[t][24];
    float4 c3 = *(const float4*)&sBC[t][28];
    float bv[16] = {b0.x,b0.y,b0.z,b0.w, b1.x,b1.y,b1.z,b1.w,
                    b2.x,b2.y,b2.z,b2.w, b3.x,b3.y,b3.z,b3.w};
    float cv[16] = {c0.x,c0.y,c0.z,c0.w, c1.x,c1.y,c1.z,c1.w,
                    c2.x,c2.y,c2.z,c2.w, c3.x,c3.y,c3.z,c3.w};
    float dtx = dtv * xv;
    float y = 0.f;
    #pragma unroll
    for (int s = 0; s < 16; ++s) {
      float dA = __expf(dtv * A[s]);
      h[s] = fmaf(dA, h[s], dtx * bv[s]);
      y = fmaf(h[s], cv[s], y);
    }
    y = fmaf(Dv, xv, y);
    float sig = 1.f / (1.f + __expf(-zv));
    yp[(size_t)t * DI] = f2bf(y * (zv * sig));
  }
}

// ---------------- final LN + residual, write (B,192,H,W) ----------------
__global__ __launch_bounds__(256) void ln_out_kernel(
    const float* __restrict__ outp, const float* __restrict__ g,
    const float* __restrict__ b, const float* __restrict__ xs,
    float* __restrict__ out)
{
  int wave = threadIdx.x >> 6;
  int lane = threadIdx.x & 63;
  int r = blockIdx.x * 4 + wave;
  int bb = r >> 10, n = r & 1023;
  const float* xr = outp + (size_t)r * DM;
  float v[3];
  float s = 0.f, s2 = 0.f;
  #pragma unroll
  for (int j = 0; j < 3; ++j) {
    int c = lane + j * 64;
    v[j] = xr[c];
    s += v[j]; s2 += v[j] * v[j];
  }
  s = wave_sum(s); s2 = wave_sum(s2);
  float mean = s * (1.f / DM);
  float var  = s2 * (1.f / DM) - mean * mean;
  float rstd = rsqrtf(var + 1e-5f);
  const float* xsr = xs + (size_t)r * DM;
  #pragma unroll
  for (int j = 0; j < 3; ++j) {
    int c = lane + j * 64;
    out[(size_t)bb * DM * L + (size_t)c * L + n] =
        (v[j] - mean) * rstd * g[c] + b[c] + xsr[c];
  }
}

// ---------------- host side ----------------
static inline void gemm64(const ushortx* A, int lda, const ushortx* W, const float* bias,
                          float* C, ushortx* Cb,
                          int N, int K, int ldc, int coff, int4 perm, int act,
                          int nz, long astride, long wstride, long cstride, int coffstride,
                          hipStream_t s) {
  dim3 grid(ROWS / 128, (N + 63) / 64, nz);
  gemm_kernel<64><<<grid, 256, 0, s>>>(A, lda, W, bias, C, Cb, N, K, ldc, coff, perm, act,
                                       astride, wstride, cstride, coffstride);
}
static inline void gemm128(const ushortx* A, int lda, const ushortx* W, const float* bias,
                           float* C, ushortx* Cb,
                           int N, int K, int ldc, int coff, int4 perm, int act,
                           int nz, long astride, long wstride, long cstride, int coffstride,
                           hipStream_t s) {
  dim3 grid(ROWS / 128, (N + 127) / 128, nz);
  gemm_kernel<128><<<grid, 256, 0, s>>>(A, lda, W, bias, C, Cb, N, K, ldc, coff, perm, act,
                                        astride, wstride, cstride, coffstride);
}

extern "C" void kernel_launch(void* const* d_in, const int* in_sizes, int n_in,
                              void* d_out, int out_size, void* d_ws, size_t ws_size,
                              hipStream_t stream) {
  (void)in_sizes; (void)n_in; (void)out_size; (void)ws_size;
  const float* x        = (const float*)d_in[0];
  const float* norm_g   = (const float*)d_in[1];
  const float* norm_b   = (const float*)d_in[2];
  const float* in_w     = (const float*)d_in[3];
  const float* in_b     = (const float*)d_in[4];
  const float* m_in_w   = (const float*)d_in[5];
  const float* m_conv_w = (const float*)d_in[6];
  const float* m_conv_b = (const float*)d_in[7];
  const float* m_xp_w   = (const float*)d_in[8];
  const float* m_dt_w   = (const float*)d_in[9];
  const float* m_dt_b   = (const float*)d_in[10];
  const float* m_Alog   = (const float*)d_in[11];
  const float* m_D      = (const float*)d_in[12];
  const float* m_out_w  = (const float*)d_in[13];
  const float* f_w1     = (const float*)d_in[14];
  const float* f_b1     = (const float*)d_in[15];
  const float* f_w2     = (const float*)d_in[16];
  const float* f_b2     = (const float*)d_in[17];
  const float* o_w      = (const float*)d_in[18];
  const float* o_b      = (const float*)d_in[19];
  const float* on_g     = (const float*)d_in[20];
  const float* on_b     = (const float*)d_in[21];
  float* out = (float*)d_out;

  // ---- workspace layout ----
  float* ws   = (float*)d_ws;
  float* xs   = ws;                        // 786432
  float* xz   = xs + 786432;               // 12582912
  float* xsm  = xz + 12582912;             // 6291456
  float* dbl  = xsm + 6291456;             // 720896
  float* dtb  = dbl + 720896;              // 6291456
  float* hseg = dtb + 6291456;             // 16*32*384*16 = 3145728
  float* Sseg = hseg + 3145728;            // 16*32*384 = 196608
  ushortx* xs_bf  = (ushortx*)(Sseg + 196608);  // 786432 sh
  ushortx* xp_bf  = xs_bf + 786432;             // 786432 sh
  ushortx* wbf    = xp_bf + 786432;             // 1394688 sh
  ushortx* shared_bf = wbf + 1394688;           // 6291456 sh (xsm_bf, later ybf)
  // xz region is dead after scan -> alias post-scan bf16/fp32 buffers into it
  ushortx* fused_bf = (ushortx*)xz;             // 3145728 sh
  ushortx* hdn_bf   = fused_bf + 3145728;       // 1572864 sh
  ushortx* h2_bf    = hdn_bf + 1572864;         // 786432 sh
  float*   outp     = xz + 2752512;             // 786432 f32 (after the 3 bf16 bufs)

  // weight offsets in wbf (shorts)
  const unsigned W_IN = 0, W_MIN = 36864, W_XP = 626688, W_OUT = 694272,
                 W_F1 = 989184, W_F2 = 1284096, W_O = 1357824;

  int4 p0 = make_int4(0, 0, 0, 0);
  int4 pfwd = make_int4(0, 1, 2, 3);
  int4 pinv = make_int4(0, 1, 2, 4);

  // 0) weights -> bf16 (once per call)
  {
    WcvtArgs a;
    a.src[0] = in_w;    a.off[0] = W_IN;  a.n[0] = 36864;
    a.src[1] = m_in_w;  a.off[1] = W_MIN; a.n[1] = 589824;
    a.src[2] = m_xp_w;  a.off[2] = W_XP;  a.n[2] = 67584;
    a.src[3] = m_out_w; a.off[3] = W_OUT; a.n[3] = 294912;
    a.src[4] = f_w1;    a.off[4] = W_F1;  a.n[4] = 294912;
    a.src[5] = f_w2;    a.off[5] = W_F2;  a.n[5] = 73728;
    a.src[6] = o_w;     a.off[6] = W_O;   a.n[6] = 36864;
    wcvt_kernel<<<dim3(576, 7), 256, 0, stream>>>(a, wbf);
  }
  // 1) input layernorm + transpose -> xs fp32 + bf16
  ln_in_kernel<<<1024, 256, 0, stream>>>(x, norm_g, norm_b, xs, xs_bf);
  // 2) xp = xs @ in_w^T + in_b  (bf16 out only)
  gemm64(xs_bf, DM, wbf + W_IN, in_b, nullptr, xp_bf, DM, DM, DM, 0, p0, 0,
         1, 0, 0, 0, 0, stream);
  // 3) xz_k = perm_k(xp) @ Win_k^T (fp32 out), one dispatch, z = direction; BN=128
  gemm128(xp_bf, DM, wbf + W_MIN, nullptr, xz, nullptr, 2 * DI, DM, 2 * DI, 0, pfwd, 0,
          4, 0, (long)2 * DI * DM, (long)ROWS * 2 * DI, 0, stream);
  // 4) depthwise causal conv + silu -> xsm fp32 + bf16
  conv_silu_kernel<<<(16 * L * DI) / 256, 256, 0, stream>>>(xz, m_conv_w, m_conv_b, xsm, shared_bf);
  // 5) dbl_k = xsm_k @ Wxp_k^T (N=44, fp32 out), one dispatch
  gemm64(shared_bf, DI, wbf + W_XP, nullptr, dbl, nullptr, 44, DI, 44, 0, p0, 0,
         4, (long)ROWS * DI, (long)44 * DI, (long)ROWS * 44, 0, stream);
  // 6) dt = softplus(dbl[:,:12] @ Wdt^T + bdt)
  dt_kernel<<<(16 * L * DI) / 256, 256, 0, stream>>>(dbl, m_dt_w, m_dt_b, dtb);
  // 7) time-segmented selective scan: pass1 -> mid (serial fold) -> pass2 (+gate) -> ybf
  scan_pass1<<<dim3(DI / 64, 16, SEG), 64, 0, stream>>>(dbl, dtb, xsm, m_Alog, hseg, Sseg);
  scan_mid<<<dim3(DI / 64, 16), 64, 0, stream>>>(hseg, Sseg, m_Alog);
  scan_pass2<<<dim3(DI / 64, 16, SEG), 64, 0, stream>>>(dbl, dtb, xz, xsm, shared_bf,
                                                        m_Alog, m_D, hseg);
  // 8) out-proj per direction (gather inverse perm), scatter into fused cols (bf16 out)
  gemm64(shared_bf, DI, wbf + W_OUT, nullptr, nullptr, fused_bf, DM, DI, 4 * DM, 0, pinv, 0,
         4, (long)ROWS * DI, (long)DM * DI, 0, DM, stream);
  // 9) MLP
  gemm64(fused_bf, 4 * DM, wbf + W_F1, f_b1, nullptr, hdn_bf, 2 * DM, 4 * DM, 2 * DM, 0, p0, 1,
         1, 0, 0, 0, 0, stream); // gelu
  gemm64(hdn_bf, 2 * DM, wbf + W_F2, f_b2, nullptr, h2_bf, DM, 2 * DM, DM, 0, p0, 0,
         1, 0, 0, 0, 0, stream);
  // 10) out proj (fp32 out)
  gemm64(h2_bf, DM, wbf + W_O, o_b, outp, nullptr, DM, DM, DM, 0, p0, 0,
         1, 0, 0, 0, 0, stream);
  // 11) final LN + residual + transpose to (B,192,H,W)
  ln_out_kernel<<<1024, 256, 0, stream>>>(outp, on_g, on_b, xs, out);
}